// Round 20
// baseline (196.575 us; speedup 1.0000x reference)
//
#include <hip/hip_runtime.h>
#include <hip/hip_bf16.h>

#define BN 2048      // B*N
#define NSEQ 512
#define D 256
#define H 128
#define R 16
#define AC 5

// ---------------- Kernel 1: per-row atom head + pj projection (unchanged, passes) ----------------
__global__ __launch_bounds__(256) void row_kernel(
    const float* __restrict__ trunk, const int* __restrict__ pad,
    const float* __restrict__ ln_g, const float* __restrict__ ln_b,
    const float* __restrict__ w_a1, const float* __restrict__ b_a1,
    const float* __restrict__ w_a2, const float* __restrict__ b_a2,
    const float* __restrict__ w_pj,
    float* __restrict__ out_atom, float* __restrict__ pj_o)
{
    const int row = blockIdx.x;   // b*NSEQ + i
    const int tid = threadIdx.x;
    __shared__ float x[D];
    __shared__ float xn[D];
    __shared__ float y[D];
    __shared__ float r1[256];
    __shared__ float r2[256];

    const float xv = trunk[(size_t)row * D + tid];
    x[tid] = xv;
    r1[tid] = xv;
    r2[tid] = xv * xv;
    __syncthreads();
    for (int s = 128; s > 0; s >>= 1) {
        if (tid < s) { r1[tid] += r1[tid + s]; r2[tid] += r2[tid + s]; }
        __syncthreads();
    }
    const float mu   = r1[0] * (1.0f / D);
    const float var  = r2[0] * (1.0f / D) - mu * mu;
    const float rstd = rsqrtf(var + 1e-5f);
    xn[tid] = (xv - mu) * rstd * ln_g[tid] + ln_b[tid];
    __syncthreads();

    float acc = b_a1[tid];
    #pragma unroll 4
    for (int d = 0; d < D; ++d) acc = fmaf(xn[d], w_a1[d * D + tid], acc);
    y[tid] = acc / (1.0f + expf(-acc));

    float p = 0.0f;
    if (tid >= H) {
        const int h = tid - H;
        #pragma unroll 4
        for (int d = 0; d < D; ++d) p = fmaf(x[d], w_pj[d * H + h], p);
    }
    __syncthreads();
    if (tid >= H) pj_o[(size_t)row * H + (tid - H)] = p;

    if (tid < AC) {
        float a = b_a2[tid];
        #pragma unroll 4
        for (int d = 0; d < D; ++d) a = fmaf(y[d], w_a2[d * AC + tid], a);
        out_atom[row * AC + tid] = (pad[row] != 0) ? 0.0f : a;
    }
}

// ---------------- Kernel 2: pair head — 8-lane group-cooperative h-split ----------------
__global__ __launch_bounds__(256) void pair_kernel(
    const float* __restrict__ trunk, const float* __restrict__ coords,
    const int* __restrict__ pad,
    const float* __restrict__ w_pi, const float* __restrict__ w_pr,
    const float* __restrict__ b_p1, const float* __restrict__ w_p2,
    const float* __restrict__ b_p2,
    const float* __restrict__ pj_i,
    float* __restrict__ cd_raw)
{
    const int row = blockIdx.x;
    const int b = row >> 9, i = row & (NSEQ - 1);
    const int tid = threadIdx.x;

    if (pad[row] != 0) {
        if (tid == 0) {
            cd_raw[row * 3 + 0] = 0.0f;
            cd_raw[row * 3 + 1] = 0.0f;
            cd_raw[row * 3 + 2] = 0.0f;
        }
        return;
    }

    __shared__ __align__(16) float s_wpr[R * H];
    __shared__ __align__(16) float s_pib[H];
    __shared__ __align__(16) float s_wp2[H];
    __shared__ float s_xi[D];
    __shared__ float s_cj[NSEQ * 3];
    __shared__ int   s_val[NSEQ];
    __shared__ int   s_jlist[NSEQ];
    __shared__ int   s_wcnt[8];
    __shared__ int   s_wbase[8];
    __shared__ int   s_M;
    __shared__ float r1[256], r2[256], r3[256];

    for (int k = tid; k < R * H; k += 256) s_wpr[k] = w_pr[k];
    s_xi[tid] = trunk[(size_t)row * D + tid];
    if (tid < H) s_wp2[tid] = w_p2[tid];
    for (int k = tid; k < NSEQ; k += 256) {
        s_val[k] = (pad[b * NSEQ + k] == 0);
        s_cj[k * 3 + 0] = coords[(b * NSEQ + k) * 3 + 0];
        s_cj[k * 3 + 1] = coords[(b * NSEQ + k) * 3 + 1];
        s_cj[k * 3 + 2] = coords[(b * NSEQ + k) * 3 + 2];
    }
    __syncthreads();

    // pi (jax): p[h] = b_p1[h] + sum_d xi[d] * Wpi[d*H + h]
    if (tid < H) {
        float p = b_p1[tid];
        #pragma unroll 4
        for (int d = 0; d < D; ++d) p = fmaf(s_xi[d], w_pi[d * H + tid], p);
        s_pib[tid] = p;
    }

    // ---- deterministic wave-ballot compaction of valid j (j != i) ----
    const int wv = tid >> 6, lane = tid & 63;
    unsigned long long bm[2];
    #pragma unroll
    for (int cc = 0; cc < 2; ++cc) {
        const int j = cc * 256 + tid;
        const int ok = (j != i) && s_val[j];
        bm[cc] = __ballot(ok);
        if (lane == 0) s_wcnt[cc * 4 + wv] = __popcll(bm[cc]);
    }
    __syncthreads();
    if (tid == 0) {
        int acc = 0;
        #pragma unroll
        for (int q = 0; q < 8; ++q) { s_wbase[q] = acc; acc += s_wcnt[q]; }
        s_M = acc;
    }
    __syncthreads();
    #pragma unroll
    for (int cc = 0; cc < 2; ++cc) {
        const int j = cc * 256 + tid;
        if ((j != i) && s_val[j]) {
            const int pos = s_wbase[cc * 4 + wv]
                          + __popcll(bm[cc] & ((1ull << lane) - 1ull));
            s_jlist[pos] = j;
        }
    }
    __syncthreads();
    const int M = s_M;

    // ---- 8-lane groups: group owns a pair, lane owns h-slices {c*32 + l*4 ..+3} ----
    const int grp = tid >> 3;   // 0..31
    const int l   = tid & 7;    // 0..7

    float cdx = 0.0f, cdy = 0.0f, cdz = 0.0f;
    {
        const float cix = s_cj[i * 3], ciy = s_cj[i * 3 + 1], ciz = s_cj[i * 3 + 2];
        const float bp2 = b_p2[0];
        const float gamma = 14.0625f;  // (15/4)^2
        for (int k0 = 0; k0 < M; k0 += 32) {
            const int k = k0 + grp;
            const bool act = (k < M);
            const int j = s_jlist[act ? k : (M - 1)];
            const float dx = cix - s_cj[j * 3];
            const float dy = ciy - s_cj[j * 3 + 1];
            const float dz = ciz - s_cj[j * 3 + 2];
            const float sq = dx * dx + dy * dy + dz * dz;
            const float dist = sqrtf(fmaxf(sq, 1e-12f));
            float rbf[R];
            #pragma unroll
            for (int r = 0; r < R; ++r) {
                const float t = dist - (float)(4.0 * r / 15.0);
                rbf[r] = __expf(-gamma * t * t);
            }
            const float* pjrow = pj_i + (size_t)(b * NSEQ + j) * H;
            float ssum = 0.0f;
            #pragma unroll
            for (int c = 0; c < 4; ++c) {
                const int h0 = c * 32 + l * 4;   // 8 lanes -> 128B contiguous
                const float4 pv = *(const float4*)(pjrow + h0);
                const float4 av = *(const float4*)(s_pib + h0);
                float t0 = av.x + pv.x, t1 = av.y + pv.y;
                float t2 = av.z + pv.z, t3 = av.w + pv.w;
                #pragma unroll
                for (int r = 0; r < R; ++r) {
                    const float rv = rbf[r];
                    const float4 w = *(const float4*)(s_wpr + r * H + h0);
                    t0 = fmaf(rv, w.x, t0);
                    t1 = fmaf(rv, w.y, t1);
                    t2 = fmaf(rv, w.z, t2);
                    t3 = fmaf(rv, w.w, t3);
                }
                const float4 w2 = *(const float4*)(s_wp2 + h0);
                t0 = t0 / (1.0f + __expf(-t0));
                t1 = t1 / (1.0f + __expf(-t1));
                t2 = t2 / (1.0f + __expf(-t2));
                t3 = t3 / (1.0f + __expf(-t3));
                ssum += t0 * w2.x + t1 * w2.y + t2 * w2.z + t3 * w2.w;
            }
            // 8-lane in-group reduce
            ssum += __shfl_xor(ssum, 4, 8);
            ssum += __shfl_xor(ssum, 2, 8);
            ssum += __shfl_xor(ssum, 1, 8);
            if (act && l == 0) {
                const float pw = ssum + bp2;
                cdx = fmaf(pw, dx, cdx);
                cdy = fmaf(pw, dy, cdy);
                cdz = fmaf(pw, dz, cdz);
            }
        }
    }
    r1[tid] = cdx; r2[tid] = cdy; r3[tid] = cdz;
    __syncthreads();
    for (int s = 128; s > 0; s >>= 1) {
        if (tid < s) { r1[tid] += r1[tid + s]; r2[tid] += r2[tid + s]; r3[tid] += r3[tid + s]; }
        __syncthreads();
    }
    if (tid == 0) {
        cd_raw[row * 3 + 0] = r1[0];
        cd_raw[row * 3 + 1] = r2[0];
        cd_raw[row * 3 + 2] = r3[0];
    }
}

// ---------------- Kernel 3: proper jax finalize (unchanged, passes) ----------------
__global__ __launch_bounds__(256) void finalize_kernel(
    const float* __restrict__ cd_raw, const int* __restrict__ pad,
    float* __restrict__ out_coord)
{
    const int b = blockIdx.x;
    const int tid = threadIdx.x;
    __shared__ float r1[256], r2[256], r3[256], r4[256];
    float sx = 0.0f, sy = 0.0f, sz = 0.0f, cnt = 0.0f;
    for (int ii = tid; ii < NSEQ; ii += 256) {
        if (pad[b * NSEQ + ii] == 0) {
            sx += cd_raw[(b * NSEQ + ii) * 3 + 0];
            sy += cd_raw[(b * NSEQ + ii) * 3 + 1];
            sz += cd_raw[(b * NSEQ + ii) * 3 + 2];
            cnt += 1.0f;
        }
    }
    r1[tid] = sx; r2[tid] = sy; r3[tid] = sz; r4[tid] = cnt;
    __syncthreads();
    for (int s = 128; s > 0; s >>= 1) {
        if (tid < s) {
            r1[tid] += r1[tid + s]; r2[tid] += r2[tid + s];
            r3[tid] += r3[tid + s]; r4[tid] += r4[tid + s];
        }
        __syncthreads();
    }
    const float denom = fmaxf(r4[0], 1.0f);
    const float inv_d = 1.0f / denom;
    const float mx = r1[0] * inv_d * inv_d;
    const float my = r2[0] * inv_d * inv_d;
    const float mz = r3[0] * inv_d * inv_d;
    for (int ii = tid; ii < NSEQ; ii += 256) {
        const bool v = (pad[b * NSEQ + ii] == 0);
        out_coord[(b * NSEQ + ii) * 3 + 0] = v ? cd_raw[(b * NSEQ + ii) * 3 + 0] * inv_d - mx : 0.0f;
        out_coord[(b * NSEQ + ii) * 3 + 1] = v ? cd_raw[(b * NSEQ + ii) * 3 + 1] * inv_d - my : 0.0f;
        out_coord[(b * NSEQ + ii) * 3 + 2] = v ? cd_raw[(b * NSEQ + ii) * 3 + 2] * inv_d - mz : 0.0f;
    }
}

extern "C" void kernel_launch(void* const* d_in, const int* in_sizes, int n_in,
                              void* d_out, int out_size, void* d_ws, size_t ws_size,
                              hipStream_t stream) {
    const float* trunk  = (const float*)d_in[0];
    const float* coords = (const float*)d_in[1];
    const int*   pad    = (const int*)d_in[2];
    const float* ln_g   = (const float*)d_in[3];
    const float* ln_b   = (const float*)d_in[4];
    const float* w_a1   = (const float*)d_in[5];
    const float* b_a1   = (const float*)d_in[6];
    const float* w_a2   = (const float*)d_in[7];
    const float* b_a2   = (const float*)d_in[8];
    const float* w_pi   = (const float*)d_in[9];
    const float* w_pj   = (const float*)d_in[10];
    const float* w_pr   = (const float*)d_in[11];
    const float* b_p1   = (const float*)d_in[12];
    const float* w_p2   = (const float*)d_in[13];
    const float* b_p2   = (const float*)d_in[14];

    float* out_atom  = (float*)d_out;                 // f32 [0:10240]
    float* out_coord = out_atom + (size_t)BN * AC;    // f32 [10240:16384]

    float* cd_raw = (float*)d_ws;
    float* pj_buf = cd_raw + (size_t)BN * 3;

    row_kernel<<<BN, 256, 0, stream>>>(trunk, pad, ln_g, ln_b, w_a1, b_a1,
                                       w_a2, b_a2, w_pj, out_atom, pj_buf);
    pair_kernel<<<BN, 256, 0, stream>>>(trunk, coords, pad, w_pi, w_pr, b_p1,
                                        w_p2, b_p2, pj_buf, cd_raw);
    finalize_kernel<<<4, 256, 0, stream>>>(cd_raw, pad, out_coord);
}

// Round 21
// 134.947 us; speedup vs baseline: 1.4567x; 1.4567x over previous
//
#include <hip/hip_runtime.h>
#include <hip/hip_bf16.h>

#define BN 2048      // B*N
#define NSEQ 512
#define D 256
#define H 128
#define R 16
#define AC 5

// ---------------- Kernel 1: per-row atom head + pj projection (unchanged, passes) ----------------
__global__ __launch_bounds__(256) void row_kernel(
    const float* __restrict__ trunk, const int* __restrict__ pad,
    const float* __restrict__ ln_g, const float* __restrict__ ln_b,
    const float* __restrict__ w_a1, const float* __restrict__ b_a1,
    const float* __restrict__ w_a2, const float* __restrict__ b_a2,
    const float* __restrict__ w_pj,
    float* __restrict__ out_atom, float* __restrict__ pj_o)
{
    const int row = blockIdx.x;   // b*NSEQ + i
    const int tid = threadIdx.x;
    __shared__ float x[D];
    __shared__ float xn[D];
    __shared__ float y[D];
    __shared__ float r1[256];
    __shared__ float r2[256];

    const float xv = trunk[(size_t)row * D + tid];
    x[tid] = xv;
    r1[tid] = xv;
    r2[tid] = xv * xv;
    __syncthreads();
    for (int s = 128; s > 0; s >>= 1) {
        if (tid < s) { r1[tid] += r1[tid + s]; r2[tid] += r2[tid + s]; }
        __syncthreads();
    }
    const float mu   = r1[0] * (1.0f / D);
    const float var  = r2[0] * (1.0f / D) - mu * mu;
    const float rstd = rsqrtf(var + 1e-5f);
    xn[tid] = (xv - mu) * rstd * ln_g[tid] + ln_b[tid];
    __syncthreads();

    float acc = b_a1[tid];
    #pragma unroll 4
    for (int d = 0; d < D; ++d) acc = fmaf(xn[d], w_a1[d * D + tid], acc);
    y[tid] = acc / (1.0f + expf(-acc));

    float p = 0.0f;
    if (tid >= H) {
        const int h = tid - H;
        #pragma unroll 4
        for (int d = 0; d < D; ++d) p = fmaf(x[d], w_pj[d * H + h], p);
    }
    __syncthreads();
    if (tid >= H) pj_o[(size_t)row * H + (tid - H)] = p;

    if (tid < AC) {
        float a = b_a2[tid];
        #pragma unroll 4
        for (int d = 0; d < D; ++d) a = fmaf(y[d], w_a2[d * AC + tid], a);
        out_atom[row * AC + tid] = (pad[row] != 0) ? 0.0f : a;
    }
}

// ---------------- Kernel 2: pair head — wave-owns-pair, lane-owns-2h ----------------
__global__ __launch_bounds__(256) void pair_kernel(
    const float* __restrict__ trunk, const float* __restrict__ coords,
    const int* __restrict__ pad,
    const float* __restrict__ w_pi, const float* __restrict__ w_pr,
    const float* __restrict__ b_p1, const float* __restrict__ w_p2,
    const float* __restrict__ b_p2,
    const float* __restrict__ pj_i,
    float* __restrict__ cd_raw)
{
    const int row = blockIdx.x;
    const int b = row >> 9, i = row & (NSEQ - 1);
    const int tid = threadIdx.x;

    if (pad[row] != 0) {
        if (tid == 0) {
            cd_raw[row * 3 + 0] = 0.0f;
            cd_raw[row * 3 + 1] = 0.0f;
            cd_raw[row * 3 + 2] = 0.0f;
        }
        return;
    }

    __shared__ __align__(16) float s_pib[H];          // pi[i]+b_p1
    __shared__ float s_xi[D];
    __shared__ __align__(16) float s_rbf[NSEQ][R];    // 32 KB, compacted pairs
    __shared__ float s_dx[NSEQ], s_dy[NSEQ], s_dz[NSEQ]; // 6 KB
    __shared__ int   s_jlist[NSEQ];                   // 2 KB
    __shared__ int   s_wcnt[8];
    __shared__ int   s_wbase[8];
    __shared__ int   s_M;
    __shared__ float rw1[4], rw2[4], rw3[4];

    s_xi[tid] = trunk[(size_t)row * D + tid];
    __syncthreads();

    // pi (jax): p[h] = b_p1[h] + sum_d xi[d] * Wpi[d*H + h]
    if (tid < H) {
        float p = b_p1[tid];
        #pragma unroll 4
        for (int d = 0; d < D; ++d) p = fmaf(s_xi[d], w_pi[d * H + tid], p);
        s_pib[tid] = p;
    }

    // ---- deterministic wave-ballot compaction of valid j (j != i) ----
    const int wv = tid >> 6, lane = tid & 63;
    unsigned long long bm[2];
    #pragma unroll
    for (int cc = 0; cc < 2; ++cc) {
        const int j = cc * 256 + tid;
        const int ok = (j != i) && (pad[b * NSEQ + j] == 0);
        bm[cc] = __ballot(ok);
        if (lane == 0) s_wcnt[cc * 4 + wv] = __popcll(bm[cc]);
    }
    __syncthreads();
    if (tid == 0) {
        int acc = 0;
        #pragma unroll
        for (int q = 0; q < 8; ++q) { s_wbase[q] = acc; acc += s_wcnt[q]; }
        s_M = acc;
    }
    __syncthreads();
    #pragma unroll
    for (int cc = 0; cc < 2; ++cc) {
        const int j = cc * 256 + tid;
        if ((j != i) && (pad[b * NSEQ + j] == 0)) {
            const int pos = s_wbase[cc * 4 + wv]
                          + __popcll(bm[cc] & ((1ull << lane) - 1ull));
            s_jlist[pos] = j;
        }
    }
    __syncthreads();
    const int M = s_M;

    // ---- pre-phase: per-pair dist/rbf/delta into LDS (no redundancy) ----
    {
        const float cix = coords[(size_t)row * 3 + 0];
        const float ciy = coords[(size_t)row * 3 + 1];
        const float ciz = coords[(size_t)row * 3 + 2];
        const float gamma = 14.0625f;  // (15/4)^2
        for (int k = tid; k < M; k += 256) {
            const int j = s_jlist[k];
            const float* cj = coords + (size_t)(b * NSEQ + j) * 3;
            const float dx = cix - cj[0];
            const float dy = ciy - cj[1];
            const float dz = ciz - cj[2];
            const float sq = dx * dx + dy * dy + dz * dz;
            const float dist = sqrtf(fmaxf(sq, 1e-12f));
            s_dx[k] = dx; s_dy[k] = dy; s_dz[k] = dz;
            #pragma unroll
            for (int r = 0; r < R; ++r) {
                const float t = dist - (float)(4.0 * r / 15.0);
                s_rbf[k][r] = __expf(-gamma * t * t);
            }
        }
    }
    __syncthreads();

    // ---- per-lane register state: wpr slice (h = 2*lane, 2*lane+1), pib, wp2 ----
    float wprA[R], wprB[R];
    #pragma unroll
    for (int r = 0; r < R; ++r) {
        const float2 wv2 = ((const float2*)(w_pr + r * H))[lane];
        wprA[r] = wv2.x;
        wprB[r] = wv2.y;
    }
    const float2 pib2 = ((const float2*)s_pib)[lane];
    const float2 wp22 = ((const float2*)w_p2)[lane];
    const float bp2 = b_p2[0];

    // ---- main loop: wave wv handles pairs k = wv, wv+4, ... ----
    float cdx = 0.0f, cdy = 0.0f, cdz = 0.0f;
    const float* pjb = pj_i + (size_t)b * NSEQ * H;

    int k = wv;
    float2 pv = make_float2(0.0f, 0.0f);
    if (k < M) pv = ((const float2*)(pjb + (size_t)s_jlist[k] * H))[lane];
    for (; k < M; k += 4) {
        const int kn = k + 4;
        float2 pvn = pv;
        if (kn < M) pvn = ((const float2*)(pjb + (size_t)s_jlist[kn] * H))[lane];  // prefetch

        float rb[R];
        #pragma unroll
        for (int r = 0; r < R; ++r) rb[r] = s_rbf[k][r];   // wave-uniform broadcast

        float t0 = pib2.x + pv.x;
        float t1 = pib2.y + pv.y;
        #pragma unroll
        for (int r = 0; r < R; ++r) {
            t0 = fmaf(rb[r], wprA[r], t0);
            t1 = fmaf(rb[r], wprB[r], t1);
        }
        t0 = t0 / (1.0f + __expf(-t0));
        t1 = t1 / (1.0f + __expf(-t1));
        float part = t0 * wp22.x + t1 * wp22.y;
        // butterfly over 64 lanes -> all lanes hold full h-sum
        part += __shfl_xor(part, 32);
        part += __shfl_xor(part, 16);
        part += __shfl_xor(part, 8);
        part += __shfl_xor(part, 4);
        part += __shfl_xor(part, 2);
        part += __shfl_xor(part, 1);
        const float pw = part + bp2;
        cdx = fmaf(pw, s_dx[k], cdx);
        cdy = fmaf(pw, s_dy[k], cdy);
        cdz = fmaf(pw, s_dz[k], cdz);
        pv = pvn;
    }
    if (lane == 0) { rw1[wv] = cdx; rw2[wv] = cdy; rw3[wv] = cdz; }
    __syncthreads();
    if (tid == 0) {
        cd_raw[row * 3 + 0] = rw1[0] + rw1[1] + rw1[2] + rw1[3];
        cd_raw[row * 3 + 1] = rw2[0] + rw2[1] + rw2[2] + rw2[3];
        cd_raw[row * 3 + 2] = rw3[0] + rw3[1] + rw3[2] + rw3[3];
    }
}

// ---------------- Kernel 3: proper jax finalize (unchanged, passes) ----------------
__global__ __launch_bounds__(256) void finalize_kernel(
    const float* __restrict__ cd_raw, const int* __restrict__ pad,
    float* __restrict__ out_coord)
{
    const int b = blockIdx.x;
    const int tid = threadIdx.x;
    __shared__ float r1[256], r2[256], r3[256], r4[256];
    float sx = 0.0f, sy = 0.0f, sz = 0.0f, cnt = 0.0f;
    for (int ii = tid; ii < NSEQ; ii += 256) {
        if (pad[b * NSEQ + ii] == 0) {
            sx += cd_raw[(b * NSEQ + ii) * 3 + 0];
            sy += cd_raw[(b * NSEQ + ii) * 3 + 1];
            sz += cd_raw[(b * NSEQ + ii) * 3 + 2];
            cnt += 1.0f;
        }
    }
    r1[tid] = sx; r2[tid] = sy; r3[tid] = sz; r4[tid] = cnt;
    __syncthreads();
    for (int s = 128; s > 0; s >>= 1) {
        if (tid < s) {
            r1[tid] += r1[tid + s]; r2[tid] += r2[tid + s];
            r3[tid] += r3[tid + s]; r4[tid] += r4[tid + s];
        }
        __syncthreads();
    }
    const float denom = fmaxf(r4[0], 1.0f);
    const float inv_d = 1.0f / denom;
    const float mx = r1[0] * inv_d * inv_d;
    const float my = r2[0] * inv_d * inv_d;
    const float mz = r3[0] * inv_d * inv_d;
    for (int ii = tid; ii < NSEQ; ii += 256) {
        const bool v = (pad[b * NSEQ + ii] == 0);
        out_coord[(b * NSEQ + ii) * 3 + 0] = v ? cd_raw[(b * NSEQ + ii) * 3 + 0] * inv_d - mx : 0.0f;
        out_coord[(b * NSEQ + ii) * 3 + 1] = v ? cd_raw[(b * NSEQ + ii) * 3 + 1] * inv_d - my : 0.0f;
        out_coord[(b * NSEQ + ii) * 3 + 2] = v ? cd_raw[(b * NSEQ + ii) * 3 + 2] * inv_d - mz : 0.0f;
    }
}

extern "C" void kernel_launch(void* const* d_in, const int* in_sizes, int n_in,
                              void* d_out, int out_size, void* d_ws, size_t ws_size,
                              hipStream_t stream) {
    const float* trunk  = (const float*)d_in[0];
    const float* coords = (const float*)d_in[1];
    const int*   pad    = (const int*)d_in[2];
    const float* ln_g   = (const float*)d_in[3];
    const float* ln_b   = (const float*)d_in[4];
    const float* w_a1   = (const float*)d_in[5];
    const float* b_a1   = (const float*)d_in[6];
    const float* w_a2   = (const float*)d_in[7];
    const float* b_a2   = (const float*)d_in[8];
    const float* w_pi   = (const float*)d_in[9];
    const float* w_pj   = (const float*)d_in[10];
    const float* w_pr   = (const float*)d_in[11];
    const float* b_p1   = (const float*)d_in[12];
    const float* w_p2   = (const float*)d_in[13];
    const float* b_p2   = (const float*)d_in[14];

    float* out_atom  = (float*)d_out;                 // f32 [0:10240]
    float* out_coord = out_atom + (size_t)BN * AC;    // f32 [10240:16384]

    float* cd_raw = (float*)d_ws;
    float* pj_buf = cd_raw + (size_t)BN * 3;

    row_kernel<<<BN, 256, 0, stream>>>(trunk, pad, ln_g, ln_b, w_a1, b_a1,
                                       w_a2, b_a2, w_pj, out_atom, pj_buf);
    pair_kernel<<<BN, 256, 0, stream>>>(trunk, coords, pad, w_pi, w_pr, b_p1,
                                        w_p2, b_p2, pj_buf, cd_raw);
    finalize_kernel<<<4, 256, 0, stream>>>(cd_raw, pad, out_coord);
}

// Round 23
// 125.586 us; speedup vs baseline: 1.5653x; 1.0745x over previous
//
#include <hip/hip_runtime.h>
#include <hip/hip_bf16.h>

#define BN 2048      // B*N
#define NSEQ 512
#define D 256
#define H 128
#define R 16
#define AC 5

// ---------------- Kernel 1: per-row atom head + pj projection (unchanged, passes) ----------------
__global__ __launch_bounds__(256) void row_kernel(
    const float* __restrict__ trunk, const int* __restrict__ pad,
    const float* __restrict__ ln_g, const float* __restrict__ ln_b,
    const float* __restrict__ w_a1, const float* __restrict__ b_a1,
    const float* __restrict__ w_a2, const float* __restrict__ b_a2,
    const float* __restrict__ w_pj,
    float* __restrict__ out_atom, float* __restrict__ pj_o)
{
    const int row = blockIdx.x;   // b*NSEQ + i
    const int tid = threadIdx.x;
    __shared__ float x[D];
    __shared__ float xn[D];
    __shared__ float y[D];
    __shared__ float r1[256];
    __shared__ float r2[256];

    const float xv = trunk[(size_t)row * D + tid];
    x[tid] = xv;
    r1[tid] = xv;
    r2[tid] = xv * xv;
    __syncthreads();
    for (int s = 128; s > 0; s >>= 1) {
        if (tid < s) { r1[tid] += r1[tid + s]; r2[tid] += r2[tid + s]; }
        __syncthreads();
    }
    const float mu   = r1[0] * (1.0f / D);
    const float var  = r2[0] * (1.0f / D) - mu * mu;
    const float rstd = rsqrtf(var + 1e-5f);
    xn[tid] = (xv - mu) * rstd * ln_g[tid] + ln_b[tid];
    __syncthreads();

    float acc = b_a1[tid];
    #pragma unroll 4
    for (int d = 0; d < D; ++d) acc = fmaf(xn[d], w_a1[d * D + tid], acc);
    y[tid] = acc / (1.0f + expf(-acc));

    float p = 0.0f;
    if (tid >= H) {
        const int h = tid - H;
        #pragma unroll 4
        for (int d = 0; d < D; ++d) p = fmaf(x[d], w_pj[d * H + h], p);
    }
    __syncthreads();
    if (tid >= H) pj_o[(size_t)row * H + (tid - H)] = p;

    if (tid < AC) {
        float a = b_a2[tid];
        #pragma unroll 4
        for (int d = 0; d < D; ++d) a = fmaf(y[d], w_a2[d * AC + tid], a);
        out_atom[row * AC + tid] = (pad[row] != 0) ? 0.0f : a;
    }
}

// ---------------- Kernel 2: pair head — wave-owns-pair, lane-owns-2h, NO per-pair reduce ----------------
__global__ __launch_bounds__(256) void pair_kernel(
    const float* __restrict__ trunk, const float* __restrict__ coords,
    const int* __restrict__ pad,
    const float* __restrict__ w_pi, const float* __restrict__ w_pr,
    const float* __restrict__ b_p1, const float* __restrict__ w_p2,
    const float* __restrict__ b_p2,
    const float* __restrict__ pj_i,
    float* __restrict__ cd_raw)
{
    const int row = blockIdx.x;
    const int b = row >> 9, i = row & (NSEQ - 1);
    const int tid = threadIdx.x;

    if (pad[row] != 0) {
        if (tid == 0) {
            cd_raw[row * 3 + 0] = 0.0f;
            cd_raw[row * 3 + 1] = 0.0f;
            cd_raw[row * 3 + 2] = 0.0f;
        }
        return;
    }

    __shared__ __align__(16) float s_pib[H];            // pi[i]+b_p1
    __shared__ float s_xi[D];
    __shared__ __align__(16) float s_rbf[NSEQ][R];      // 32 KB, compacted
    __shared__ __align__(16) float4 s_d4[NSEQ];         // 8 KB  (dx,dy,dz,-)
    __shared__ int   s_jlist[NSEQ];                     // 2 KB
    __shared__ int   s_wcnt[8];
    __shared__ int   s_wbase[8];
    __shared__ int   s_M;
    __shared__ float rw1[4], rw2[4], rw3[4];

    s_xi[tid] = trunk[(size_t)row * D + tid];
    __syncthreads();

    // pi (jax): p[h] = b_p1[h] + sum_d xi[d] * Wpi[d*H + h]
    if (tid < H) {
        float p = b_p1[tid];
        #pragma unroll 4
        for (int d = 0; d < D; ++d) p = fmaf(s_xi[d], w_pi[d * H + tid], p);
        s_pib[tid] = p;
    }

    // ---- deterministic wave-ballot compaction of valid j (j != i) ----
    const int wv = tid >> 6, lane = tid & 63;
    unsigned long long bm[2];
    #pragma unroll
    for (int cc = 0; cc < 2; ++cc) {
        const int j = cc * 256 + tid;
        const int ok = (j != i) && (pad[b * NSEQ + j] == 0);
        bm[cc] = __ballot(ok);
        if (lane == 0) s_wcnt[cc * 4 + wv] = __popcll(bm[cc]);
    }
    __syncthreads();
    if (tid == 0) {
        int acc = 0;
        #pragma unroll
        for (int q = 0; q < 8; ++q) { s_wbase[q] = acc; acc += s_wcnt[q]; }
        s_M = acc;
    }
    __syncthreads();
    #pragma unroll
    for (int cc = 0; cc < 2; ++cc) {
        const int j = cc * 256 + tid;
        if ((j != i) && (pad[b * NSEQ + j] == 0)) {
            const int pos = s_wbase[cc * 4 + wv]
                          + __popcll(bm[cc] & ((1ull << lane) - 1ull));
            s_jlist[pos] = j;
        }
    }
    __syncthreads();
    const int M = s_M;

    // ---- pre-phase: per-pair delta/rbf into LDS (float4 stores) ----
    {
        const float cix = coords[(size_t)row * 3 + 0];
        const float ciy = coords[(size_t)row * 3 + 1];
        const float ciz = coords[(size_t)row * 3 + 2];
        const float gamma = 14.0625f;  // (15/4)^2
        for (int k = tid; k < M; k += 256) {
            const int j = s_jlist[k];
            const float* cj = coords + (size_t)(b * NSEQ + j) * 3;
            const float dx = cix - cj[0];
            const float dy = ciy - cj[1];
            const float dz = ciz - cj[2];
            const float sq = dx * dx + dy * dy + dz * dz;
            const float dist = sqrtf(fmaxf(sq, 1e-12f));
            s_d4[k] = make_float4(dx, dy, dz, 0.0f);
            #pragma unroll
            for (int c = 0; c < 4; ++c) {
                float4 q;
                {
                    const float t0 = dist - (float)(4.0 * (4 * c + 0) / 15.0);
                    const float t1 = dist - (float)(4.0 * (4 * c + 1) / 15.0);
                    const float t2 = dist - (float)(4.0 * (4 * c + 2) / 15.0);
                    const float t3 = dist - (float)(4.0 * (4 * c + 3) / 15.0);
                    q.x = __expf(-gamma * t0 * t0);
                    q.y = __expf(-gamma * t1 * t1);
                    q.z = __expf(-gamma * t2 * t2);
                    q.w = __expf(-gamma * t3 * t3);
                }
                ((float4*)s_rbf[k])[c] = q;
            }
        }
    }
    __syncthreads();

    // ---- per-lane register state: wpr slice (h = 2*lane, 2*lane+1), pib, wp2 ----
    float wprA[R], wprB[R];
    #pragma unroll
    for (int r = 0; r < R; ++r) {
        const float2 wv2 = ((const float2*)(w_pr + r * H))[lane];
        wprA[r] = wv2.x;
        wprB[r] = wv2.y;
    }
    const float2 pib2 = ((const float2*)s_pib)[lane];
    const float2 wp22 = ((const float2*)w_p2)[lane];
    const float bp2 = b_p2[0];

    // ---- main loop: wave wv handles pairs k = wv, wv+4, ...  (no per-pair reduce!) ----
    float cdx = 0.0f, cdy = 0.0f, cdz = 0.0f;       // per-lane partial of sum part*d
    float sdx = 0.0f, sdy = 0.0f, sdz = 0.0f;       // uniform sum of d (for bp2 term)
    const float* pjb = pj_i + (size_t)b * NSEQ * H;

    int k = wv;
    float2 pv = make_float2(0.0f, 0.0f);
    if (k < M) pv = ((const float2*)(pjb + (size_t)s_jlist[k] * H))[lane];
    for (; k < M; k += 4) {
        const int kn = k + 4;
        float2 pvn = pv;
        if (kn < M) pvn = ((const float2*)(pjb + (size_t)s_jlist[kn] * H))[lane];  // prefetch

        const float4 q0 = ((const float4*)s_rbf[k])[0];   // wave-uniform broadcast
        const float4 q1 = ((const float4*)s_rbf[k])[1];
        const float4 q2 = ((const float4*)s_rbf[k])[2];
        const float4 q3 = ((const float4*)s_rbf[k])[3];
        const float4 dk = s_d4[k];

        float t0 = pib2.x + pv.x;
        float t1 = pib2.y + pv.y;
        t0 = fmaf(q0.x, wprA[0],  t0); t1 = fmaf(q0.x, wprB[0],  t1);
        t0 = fmaf(q0.y, wprA[1],  t0); t1 = fmaf(q0.y, wprB[1],  t1);
        t0 = fmaf(q0.z, wprA[2],  t0); t1 = fmaf(q0.z, wprB[2],  t1);
        t0 = fmaf(q0.w, wprA[3],  t0); t1 = fmaf(q0.w, wprB[3],  t1);
        t0 = fmaf(q1.x, wprA[4],  t0); t1 = fmaf(q1.x, wprB[4],  t1);
        t0 = fmaf(q1.y, wprA[5],  t0); t1 = fmaf(q1.y, wprB[5],  t1);
        t0 = fmaf(q1.z, wprA[6],  t0); t1 = fmaf(q1.z, wprB[6],  t1);
        t0 = fmaf(q1.w, wprA[7],  t0); t1 = fmaf(q1.w, wprB[7],  t1);
        t0 = fmaf(q2.x, wprA[8],  t0); t1 = fmaf(q2.x, wprB[8],  t1);
        t0 = fmaf(q2.y, wprA[9],  t0); t1 = fmaf(q2.y, wprB[9],  t1);
        t0 = fmaf(q2.z, wprA[10], t0); t1 = fmaf(q2.z, wprB[10], t1);
        t0 = fmaf(q2.w, wprA[11], t0); t1 = fmaf(q2.w, wprB[11], t1);
        t0 = fmaf(q3.x, wprA[12], t0); t1 = fmaf(q3.x, wprB[12], t1);
        t0 = fmaf(q3.y, wprA[13], t0); t1 = fmaf(q3.y, wprB[13], t1);
        t0 = fmaf(q3.z, wprA[14], t0); t1 = fmaf(q3.z, wprB[14], t1);
        t0 = fmaf(q3.w, wprA[15], t0); t1 = fmaf(q3.w, wprB[15], t1);
        t0 = t0 / (1.0f + __expf(-t0));
        t1 = t1 / (1.0f + __expf(-t1));
        const float part = t0 * wp22.x + t1 * wp22.y;   // this lane's h-slice of pw
        cdx = fmaf(part, dk.x, cdx);
        cdy = fmaf(part, dk.y, cdy);
        cdz = fmaf(part, dk.z, cdz);
        sdx += dk.x; sdy += dk.y; sdz += dk.z;
        pv = pvn;
    }
    // one butterfly per wave (not per pair)
    #pragma unroll
    for (int off = 32; off; off >>= 1) {
        cdx += __shfl_xor(cdx, off);
        cdy += __shfl_xor(cdy, off);
        cdz += __shfl_xor(cdz, off);
    }
    if (lane == 0) {
        rw1[wv] = cdx + bp2 * sdx;   // sdx uniform across lanes of this wave
        rw2[wv] = cdy + bp2 * sdy;
        rw3[wv] = cdz + bp2 * sdz;
    }
    __syncthreads();
    if (tid == 0) {
        cd_raw[row * 3 + 0] = rw1[0] + rw1[1] + rw1[2] + rw1[3];
        cd_raw[row * 3 + 1] = rw2[0] + rw2[1] + rw2[2] + rw2[3];
        cd_raw[row * 3 + 2] = rw3[0] + rw3[1] + rw3[2] + rw3[3];
    }
}

// ---------------- Kernel 3: proper jax finalize (unchanged, passes) ----------------
__global__ __launch_bounds__(256) void finalize_kernel(
    const float* __restrict__ cd_raw, const int* __restrict__ pad,
    float* __restrict__ out_coord)
{
    const int b = blockIdx.x;
    const int tid = threadIdx.x;
    __shared__ float r1[256], r2[256], r3[256], r4[256];
    float sx = 0.0f, sy = 0.0f, sz = 0.0f, cnt = 0.0f;
    for (int ii = tid; ii < NSEQ; ii += 256) {
        if (pad[b * NSEQ + ii] == 0) {
            sx += cd_raw[(b * NSEQ + ii) * 3 + 0];
            sy += cd_raw[(b * NSEQ + ii) * 3 + 1];
            sz += cd_raw[(b * NSEQ + ii) * 3 + 2];
            cnt += 1.0f;
        }
    }
    r1[tid] = sx; r2[tid] = sy; r3[tid] = sz; r4[tid] = cnt;
    __syncthreads();
    for (int s = 128; s > 0; s >>= 1) {
        if (tid < s) {
            r1[tid] += r1[tid + s]; r2[tid] += r2[tid + s];
            r3[tid] += r3[tid + s]; r4[tid] += r4[tid + s];
        }
        __syncthreads();
    }
    const float denom = fmaxf(r4[0], 1.0f);
    const float inv_d = 1.0f / denom;
    const float mx = r1[0] * inv_d * inv_d;
    const float my = r2[0] * inv_d * inv_d;
    const float mz = r3[0] * inv_d * inv_d;
    for (int ii = tid; ii < NSEQ; ii += 256) {
        const bool v = (pad[b * NSEQ + ii] == 0);
        out_coord[(b * NSEQ + ii) * 3 + 0] = v ? cd_raw[(b * NSEQ + ii) * 3 + 0] * inv_d - mx : 0.0f;
        out_coord[(b * NSEQ + ii) * 3 + 1] = v ? cd_raw[(b * NSEQ + ii) * 3 + 1] * inv_d - my : 0.0f;
        out_coord[(b * NSEQ + ii) * 3 + 2] = v ? cd_raw[(b * NSEQ + ii) * 3 + 2] * inv_d - mz : 0.0f;
    }
}

extern "C" void kernel_launch(void* const* d_in, const int* in_sizes, int n_in,
                              void* d_out, int out_size, void* d_ws, size_t ws_size,
                              hipStream_t stream) {
    const float* trunk  = (const float*)d_in[0];
    const float* coords = (const float*)d_in[1];
    const int*   pad    = (const int*)d_in[2];
    const float* ln_g   = (const float*)d_in[3];
    const float* ln_b   = (const float*)d_in[4];
    const float* w_a1   = (const float*)d_in[5];
    const float* b_a1   = (const float*)d_in[6];
    const float* w_a2   = (const float*)d_in[7];
    const float* b_a2   = (const float*)d_in[8];
    const float* w_pi   = (const float*)d_in[9];
    const float* w_pj   = (const float*)d_in[10];
    const float* w_pr   = (const float*)d_in[11];
    const float* b_p1   = (const float*)d_in[12];
    const float* w_p2   = (const float*)d_in[13];
    const float* b_p2   = (const float*)d_in[14];

    float* out_atom  = (float*)d_out;                 // f32 [0:10240]
    float* out_coord = out_atom + (size_t)BN * AC;    // f32 [10240:16384]

    float* cd_raw = (float*)d_ws;
    float* pj_buf = cd_raw + (size_t)BN * 3;

    row_kernel<<<BN, 256, 0, stream>>>(trunk, pad, ln_g, ln_b, w_a1, b_a1,
                                       w_a2, b_a2, w_pj, out_atom, pj_buf);
    pair_kernel<<<BN, 256, 0, stream>>>(trunk, coords, pad, w_pi, w_pr, b_p1,
                                        w_p2, b_p2, pj_buf, cd_raw);
    finalize_kernel<<<4, 256, 0, stream>>>(cd_raw, pad, out_coord);
}

// Round 26
// 101.376 us; speedup vs baseline: 1.9391x; 1.2388x over previous
//
#include <hip/hip_runtime.h>
#include <hip/hip_bf16.h>

#define BN 2048      // B*N
#define NSEQ 512
#define D 256
#define H 128
#define R 16
#define AC 5
#define CHUNK 128

// ---------------- Kernel 1: per-row atom head + pj projection (unchanged, passes) ----------------
__global__ __launch_bounds__(256) void row_kernel(
    const float* __restrict__ trunk, const int* __restrict__ pad,
    const float* __restrict__ ln_g, const float* __restrict__ ln_b,
    const float* __restrict__ w_a1, const float* __restrict__ b_a1,
    const float* __restrict__ w_a2, const float* __restrict__ b_a2,
    const float* __restrict__ w_pj,
    float* __restrict__ out_atom, float* __restrict__ pj_o)
{
    const int row = blockIdx.x;   // b*NSEQ + i
    const int tid = threadIdx.x;
    __shared__ float x[D];
    __shared__ float xn[D];
    __shared__ float y[D];
    __shared__ float r1[256];
    __shared__ float r2[256];

    const float xv = trunk[(size_t)row * D + tid];
    x[tid] = xv;
    r1[tid] = xv;
    r2[tid] = xv * xv;
    __syncthreads();
    for (int s = 128; s > 0; s >>= 1) {
        if (tid < s) { r1[tid] += r1[tid + s]; r2[tid] += r2[tid + s]; }
        __syncthreads();
    }
    const float mu   = r1[0] * (1.0f / D);
    const float var  = r2[0] * (1.0f / D) - mu * mu;
    const float rstd = rsqrtf(var + 1e-5f);
    xn[tid] = (xv - mu) * rstd * ln_g[tid] + ln_b[tid];
    __syncthreads();

    float acc = b_a1[tid];
    #pragma unroll 4
    for (int d = 0; d < D; ++d) acc = fmaf(xn[d], w_a1[d * D + tid], acc);
    y[tid] = acc / (1.0f + expf(-acc));

    float p = 0.0f;
    if (tid >= H) {
        const int h = tid - H;
        #pragma unroll 4
        for (int d = 0; d < D; ++d) p = fmaf(x[d], w_pj[d * H + h], p);
    }
    __syncthreads();
    if (tid >= H) pj_o[(size_t)row * H + (tid - H)] = p;

    if (tid < AC) {
        float a = b_a2[tid];
        #pragma unroll 4
        for (int d = 0; d < D; ++d) a = fmaf(y[d], w_a2[d * AC + tid], a);
        out_atom[row * AC + tid] = (pad[row] != 0) ? 0.0f : a;
    }
}

// ---------------- Kernel 2: pair head — chunked LDS (high occupancy) + split FMA chains ----------------
__global__ __launch_bounds__(256) void pair_kernel(
    const float* __restrict__ trunk, const float* __restrict__ coords,
    const int* __restrict__ pad,
    const float* __restrict__ w_pi, const float* __restrict__ w_pr,
    const float* __restrict__ b_p1, const float* __restrict__ w_p2,
    const float* __restrict__ b_p2,
    const float* __restrict__ pj_i,
    float* __restrict__ cd_raw)
{
    const int row = blockIdx.x;
    const int b = row >> 9, i = row & (NSEQ - 1);
    const int tid = threadIdx.x;

    if (pad[row] != 0) {
        if (tid == 0) {
            cd_raw[row * 3 + 0] = 0.0f;
            cd_raw[row * 3 + 1] = 0.0f;
            cd_raw[row * 3 + 2] = 0.0f;
        }
        return;
    }

    __shared__ __align__(16) float s_pib[H];          // 512 B
    __shared__ float s_xi[D];                         // 1 KB
    __shared__ __align__(16) float s_rbf[CHUNK][20];  // 10 KB (stride-20: rows 80B, f4-aligned)
    __shared__ __align__(16) float4 s_d4[CHUNK];      // 2 KB
    __shared__ int   s_jlist[NSEQ];                   // 2 KB
    __shared__ int   s_wcnt[8];
    __shared__ int   s_wbase[8];
    __shared__ int   s_M;
    __shared__ float rw1[4], rw2[4], rw3[4];

    s_xi[tid] = trunk[(size_t)row * D + tid];
    __syncthreads();

    // pi (jax): p[h] = b_p1[h] + sum_d xi[d] * Wpi[d*H + h]
    if (tid < H) {
        float p = b_p1[tid];
        #pragma unroll 4
        for (int d = 0; d < D; ++d) p = fmaf(s_xi[d], w_pi[d * H + tid], p);
        s_pib[tid] = p;
    }

    // ---- deterministic wave-ballot compaction of valid j (j != i) ----
    const int wv = tid >> 6, lane = tid & 63;
    unsigned long long bm[2];
    #pragma unroll
    for (int cc = 0; cc < 2; ++cc) {
        const int j = cc * 256 + tid;
        const int ok = (j != i) && (pad[b * NSEQ + j] == 0);
        bm[cc] = __ballot(ok);
        if (lane == 0) s_wcnt[cc * 4 + wv] = __popcll(bm[cc]);
    }
    __syncthreads();
    if (tid == 0) {
        int acc = 0;
        #pragma unroll
        for (int q = 0; q < 8; ++q) { s_wbase[q] = acc; acc += s_wcnt[q]; }
        s_M = acc;
    }
    __syncthreads();
    #pragma unroll
    for (int cc = 0; cc < 2; ++cc) {
        const int j = cc * 256 + tid;
        if ((j != i) && (pad[b * NSEQ + j] == 0)) {
            const int pos = s_wbase[cc * 4 + wv]
                          + __popcll(bm[cc] & ((1ull << lane) - 1ull));
            s_jlist[pos] = j;
        }
    }
    __syncthreads();
    const int M = s_M;

    // ---- per-lane register state: wpr slice (h = 2*lane, 2*lane+1), pib, wp2 ----
    float wprA[R], wprB[R];
    #pragma unroll
    for (int r = 0; r < R; ++r) {
        const float2 wv2 = ((const float2*)(w_pr + r * H))[lane];
        wprA[r] = wv2.x;
        wprB[r] = wv2.y;
    }
    const float2 pib2 = ((const float2*)s_pib)[lane];
    const float2 wp22 = ((const float2*)w_p2)[lane];
    const float bp2 = b_p2[0];
    const float cix = coords[(size_t)row * 3 + 0];
    const float ciy = coords[(size_t)row * 3 + 1];
    const float ciz = coords[(size_t)row * 3 + 2];

    float cdx = 0.0f, cdy = 0.0f, cdz = 0.0f;       // per-lane partial of sum part*d
    float sdx = 0.0f, sdy = 0.0f, sdz = 0.0f;       // uniform sum of d (bp2 term)
    const float* pjb = pj_i + (size_t)b * NSEQ * H;
    const float gamma = 14.0625f;  // (15/4)^2

    for (int c0 = 0; c0 < M; c0 += CHUNK) {
        const int cn = (M - c0 < CHUNK) ? (M - c0) : CHUNK;
        __syncthreads();   // previous chunk fully consumed
        // ---- pre-phase: this chunk's delta/rbf into LDS ----
        if (tid < cn) {
            const int k = tid;
            const int j = s_jlist[c0 + k];
            const float* cj = coords + (size_t)(b * NSEQ + j) * 3;
            const float dx = cix - cj[0];
            const float dy = ciy - cj[1];
            const float dz = ciz - cj[2];
            const float sq = dx * dx + dy * dy + dz * dz;
            const float dist = sqrtf(fmaxf(sq, 1e-12f));
            s_d4[k] = make_float4(dx, dy, dz, 0.0f);
            #pragma unroll
            for (int c = 0; c < 4; ++c) {
                float4 q;
                const float t0 = dist - (float)(4.0 * (4 * c + 0) / 15.0);
                const float t1 = dist - (float)(4.0 * (4 * c + 1) / 15.0);
                const float t2 = dist - (float)(4.0 * (4 * c + 2) / 15.0);
                const float t3 = dist - (float)(4.0 * (4 * c + 3) / 15.0);
                q.x = __expf(-gamma * t0 * t0);
                q.y = __expf(-gamma * t1 * t1);
                q.z = __expf(-gamma * t2 * t2);
                q.w = __expf(-gamma * t3 * t3);
                *(float4*)(&s_rbf[k][4 * c]) = q;
            }
        }
        __syncthreads();
        // ---- main loop: wave wv handles k = wv, wv+4, ... within chunk ----
        for (int k = wv; k < cn; k += 4) {
            const float2 pv = ((const float2*)(pjb + (size_t)s_jlist[c0 + k] * H))[lane];
            const float4 q0 = *(const float4*)(&s_rbf[k][0]);    // broadcast (free)
            const float4 q1 = *(const float4*)(&s_rbf[k][4]);
            const float4 q2 = *(const float4*)(&s_rbf[k][8]);
            const float4 q3 = *(const float4*)(&s_rbf[k][12]);
            const float4 dk = s_d4[k];

            // split chains: even r -> a, odd r -> b (8-deep each)
            float t0a = pib2.x + pv.x, t0b = 0.0f;
            float t1a = pib2.y + pv.y, t1b = 0.0f;
            t0a = fmaf(q0.x, wprA[0],  t0a); t0b = fmaf(q0.y, wprA[1],  t0b);
            t1a = fmaf(q0.x, wprB[0],  t1a); t1b = fmaf(q0.y, wprB[1],  t1b);
            t0a = fmaf(q0.z, wprA[2],  t0a); t0b = fmaf(q0.w, wprA[3],  t0b);
            t1a = fmaf(q0.z, wprB[2],  t1a); t1b = fmaf(q0.w, wprB[3],  t1b);
            t0a = fmaf(q1.x, wprA[4],  t0a); t0b = fmaf(q1.y, wprA[5],  t0b);
            t1a = fmaf(q1.x, wprB[4],  t1a); t1b = fmaf(q1.y, wprB[5],  t1b);
            t0a = fmaf(q1.z, wprA[6],  t0a); t0b = fmaf(q1.w, wprA[7],  t0b);
            t1a = fmaf(q1.z, wprB[6],  t1a); t1b = fmaf(q1.w, wprB[7],  t1b);
            t0a = fmaf(q2.x, wprA[8],  t0a); t0b = fmaf(q2.y, wprA[9],  t0b);
            t1a = fmaf(q2.x, wprB[8],  t1a); t1b = fmaf(q2.y, wprB[9],  t1b);
            t0a = fmaf(q2.z, wprA[10], t0a); t0b = fmaf(q2.w, wprA[11], t0b);
            t1a = fmaf(q2.z, wprB[10], t1a); t1b = fmaf(q2.w, wprB[11], t1b);
            t0a = fmaf(q3.x, wprA[12], t0a); t0b = fmaf(q3.y, wprA[13], t0b);
            t1a = fmaf(q3.x, wprB[12], t1a); t1b = fmaf(q3.y, wprB[13], t1b);
            t0a = fmaf(q3.z, wprA[14], t0a); t0b = fmaf(q3.w, wprA[15], t0b);
            t1a = fmaf(q3.z, wprB[14], t1a); t1b = fmaf(q3.w, wprB[15], t1b);
            float t0 = t0a + t0b;
            float t1 = t1a + t1b;
            t0 = t0 / (1.0f + __expf(-t0));
            t1 = t1 / (1.0f + __expf(-t1));
            const float part = t0 * wp22.x + t1 * wp22.y;   // lane's h-slice of pw
            cdx = fmaf(part, dk.x, cdx);
            cdy = fmaf(part, dk.y, cdy);
            cdz = fmaf(part, dk.z, cdz);
            sdx += dk.x; sdy += dk.y; sdz += dk.z;
        }
    }
    // one butterfly per wave (not per pair)
    #pragma unroll
    for (int off = 32; off; off >>= 1) {
        cdx += __shfl_xor(cdx, off);
        cdy += __shfl_xor(cdy, off);
        cdz += __shfl_xor(cdz, off);
    }
    if (lane == 0) {
        rw1[wv] = cdx + bp2 * sdx;   // sdx uniform across lanes of this wave
        rw2[wv] = cdy + bp2 * sdy;
        rw3[wv] = cdz + bp2 * sdz;
    }
    __syncthreads();
    if (tid == 0) {
        cd_raw[row * 3 + 0] = rw1[0] + rw1[1] + rw1[2] + rw1[3];
        cd_raw[row * 3 + 1] = rw2[0] + rw2[1] + rw2[2] + rw2[3];
        cd_raw[row * 3 + 2] = rw3[0] + rw3[1] + rw3[2] + rw3[3];
    }
}

// ---------------- Kernel 3: proper jax finalize (unchanged, passes) ----------------
__global__ __launch_bounds__(256) void finalize_kernel(
    const float* __restrict__ cd_raw, const int* __restrict__ pad,
    float* __restrict__ out_coord)
{
    const int b = blockIdx.x;
    const int tid = threadIdx.x;
    __shared__ float r1[256], r2[256], r3[256], r4[256];
    float sx = 0.0f, sy = 0.0f, sz = 0.0f, cnt = 0.0f;
    for (int ii = tid; ii < NSEQ; ii += 256) {
        if (pad[b * NSEQ + ii] == 0) {
            sx += cd_raw[(b * NSEQ + ii) * 3 + 0];
            sy += cd_raw[(b * NSEQ + ii) * 3 + 1];
            sz += cd_raw[(b * NSEQ + ii) * 3 + 2];
            cnt += 1.0f;
        }
    }
    r1[tid] = sx; r2[tid] = sy; r3[tid] = sz; r4[tid] = cnt;
    __syncthreads();
    for (int s = 128; s > 0; s >>= 1) {
        if (tid < s) {
            r1[tid] += r1[tid + s]; r2[tid] += r2[tid + s];
            r3[tid] += r3[tid + s]; r4[tid] += r4[tid + s];
        }
        __syncthreads();
    }
    const float denom = fmaxf(r4[0], 1.0f);
    const float inv_d = 1.0f / denom;
    const float mx = r1[0] * inv_d * inv_d;
    const float my = r2[0] * inv_d * inv_d;
    const float mz = r3[0] * inv_d * inv_d;
    for (int ii = tid; ii < NSEQ; ii += 256) {
        const bool v = (pad[b * NSEQ + ii] == 0);
        out_coord[(b * NSEQ + ii) * 3 + 0] = v ? cd_raw[(b * NSEQ + ii) * 3 + 0] * inv_d - mx : 0.0f;
        out_coord[(b * NSEQ + ii) * 3 + 1] = v ? cd_raw[(b * NSEQ + ii) * 3 + 1] * inv_d - my : 0.0f;
        out_coord[(b * NSEQ + ii) * 3 + 2] = v ? cd_raw[(b * NSEQ + ii) * 3 + 2] * inv_d - mz : 0.0f;
    }
}

extern "C" void kernel_launch(void* const* d_in, const int* in_sizes, int n_in,
                              void* d_out, int out_size, void* d_ws, size_t ws_size,
                              hipStream_t stream) {
    const float* trunk  = (const float*)d_in[0];
    const float* coords = (const float*)d_in[1];
    const int*   pad    = (const int*)d_in[2];
    const float* ln_g   = (const float*)d_in[3];
    const float* ln_b   = (const float*)d_in[4];
    const float* w_a1   = (const float*)d_in[5];
    const float* b_a1   = (const float*)d_in[6];
    const float* w_a2   = (const float*)d_in[7];
    const float* b_a2   = (const float*)d_in[8];
    const float* w_pi   = (const float*)d_in[9];
    const float* w_pj   = (const float*)d_in[10];
    const float* w_pr   = (const float*)d_in[11];
    const float* b_p1   = (const float*)d_in[12];
    const float* w_p2   = (const float*)d_in[13];
    const float* b_p2   = (const float*)d_in[14];

    float* out_atom  = (float*)d_out;                 // f32 [0:10240]
    float* out_coord = out_atom + (size_t)BN * AC;    // f32 [10240:16384]

    float* cd_raw = (float*)d_ws;
    float* pj_buf = cd_raw + (size_t)BN * 3;

    row_kernel<<<BN, 256, 0, stream>>>(trunk, pad, ln_g, ln_b, w_a1, b_a1,
                                       w_a2, b_a2, w_pj, out_atom, pj_buf);
    pair_kernel<<<BN, 256, 0, stream>>>(trunk, coords, pad, w_pi, w_pr, b_p1,
                                        w_p2, b_p2, pj_buf, cd_raw);
    finalize_kernel<<<4, 256, 0, stream>>>(cd_raw, pad, out_coord);
}

// Round 27
// 100.135 us; speedup vs baseline: 1.9631x; 1.0124x over previous
//
#include <hip/hip_runtime.h>
#include <hip/hip_bf16.h>

#define BN 2048      // B*N
#define NSEQ 512
#define D 256
#define H 128
#define R 16
#define AC 5
#define CHUNK 128

__device__ __forceinline__ float fast_silu(float t) {
    const float e = __expf(-t);
    return t * __builtin_amdgcn_rcpf(1.0f + e);
}

// ---------------- Kernel 1: per-row atom head + pj projection (unchanged, passes) ----------------
__global__ __launch_bounds__(256) void row_kernel(
    const float* __restrict__ trunk, const int* __restrict__ pad,
    const float* __restrict__ ln_g, const float* __restrict__ ln_b,
    const float* __restrict__ w_a1, const float* __restrict__ b_a1,
    const float* __restrict__ w_a2, const float* __restrict__ b_a2,
    const float* __restrict__ w_pj,
    float* __restrict__ out_atom, float* __restrict__ pj_o)
{
    const int row = blockIdx.x;   // b*NSEQ + i
    const int tid = threadIdx.x;
    __shared__ float x[D];
    __shared__ float xn[D];
    __shared__ float y[D];
    __shared__ float r1[256];
    __shared__ float r2[256];

    const float xv = trunk[(size_t)row * D + tid];
    x[tid] = xv;
    r1[tid] = xv;
    r2[tid] = xv * xv;
    __syncthreads();
    for (int s = 128; s > 0; s >>= 1) {
        if (tid < s) { r1[tid] += r1[tid + s]; r2[tid] += r2[tid + s]; }
        __syncthreads();
    }
    const float mu   = r1[0] * (1.0f / D);
    const float var  = r2[0] * (1.0f / D) - mu * mu;
    const float rstd = rsqrtf(var + 1e-5f);
    xn[tid] = (xv - mu) * rstd * ln_g[tid] + ln_b[tid];
    __syncthreads();

    float acc = b_a1[tid];
    #pragma unroll 4
    for (int d = 0; d < D; ++d) acc = fmaf(xn[d], w_a1[d * D + tid], acc);
    y[tid] = acc / (1.0f + expf(-acc));   // atom path: keep precise (tight threshold)

    float p = 0.0f;
    if (tid >= H) {
        const int h = tid - H;
        #pragma unroll 4
        for (int d = 0; d < D; ++d) p = fmaf(x[d], w_pj[d * H + h], p);
    }
    __syncthreads();
    if (tid >= H) pj_o[(size_t)row * H + (tid - H)] = p;

    if (tid < AC) {
        float a = b_a2[tid];
        #pragma unroll 4
        for (int d = 0; d < D; ++d) a = fmaf(y[d], w_a2[d * AC + tid], a);
        out_atom[row * AC + tid] = (pad[row] != 0) ? 0.0f : a;
    }
}

// ---------------- Kernel 2: pair head — row split across 2 blocks + chunked LDS + fast silu ----------------
__global__ __launch_bounds__(256) void pair_kernel(
    const float* __restrict__ trunk, const float* __restrict__ coords,
    const int* __restrict__ pad,
    const float* __restrict__ w_pi, const float* __restrict__ w_pr,
    const float* __restrict__ b_p1, const float* __restrict__ w_p2,
    const float* __restrict__ b_p2,
    const float* __restrict__ pj_i,
    float* __restrict__ cd_part)   // [BN][2][3]
{
    const int row  = blockIdx.x >> 1;
    const int half = blockIdx.x & 1;
    const int b = row >> 9, i = row & (NSEQ - 1);
    const int tid = threadIdx.x;

    if (pad[row] != 0) {
        if (tid == 0) {
            cd_part[row * 6 + half * 3 + 0] = 0.0f;
            cd_part[row * 6 + half * 3 + 1] = 0.0f;
            cd_part[row * 6 + half * 3 + 2] = 0.0f;
        }
        return;
    }

    __shared__ __align__(16) float s_pib[H];          // 512 B
    __shared__ float s_xi[D];                         // 1 KB
    __shared__ __align__(16) float s_rbf[CHUNK][20];  // 10 KB
    __shared__ __align__(16) float4 s_d4[CHUNK];      // 2 KB
    __shared__ int   s_jlist[NSEQ];                   // 2 KB
    __shared__ int   s_wcnt[8];
    __shared__ int   s_wbase[8];
    __shared__ int   s_M;
    __shared__ float rw1[4], rw2[4], rw3[4];

    s_xi[tid] = trunk[(size_t)row * D + tid];
    __syncthreads();

    // pi (jax): p[h] = b_p1[h] + sum_d xi[d] * Wpi[d*H + h]
    if (tid < H) {
        float p = b_p1[tid];
        #pragma unroll 4
        for (int d = 0; d < D; ++d) p = fmaf(s_xi[d], w_pi[d * H + tid], p);
        s_pib[tid] = p;
    }

    // ---- deterministic wave-ballot compaction of valid j (j != i) ----
    const int wv = tid >> 6, lane = tid & 63;
    unsigned long long bm[2];
    #pragma unroll
    for (int cc = 0; cc < 2; ++cc) {
        const int j = cc * 256 + tid;
        const int ok = (j != i) && (pad[b * NSEQ + j] == 0);
        bm[cc] = __ballot(ok);
        if (lane == 0) s_wcnt[cc * 4 + wv] = __popcll(bm[cc]);
    }
    __syncthreads();
    if (tid == 0) {
        int acc = 0;
        #pragma unroll
        for (int q = 0; q < 8; ++q) { s_wbase[q] = acc; acc += s_wcnt[q]; }
        s_M = acc;
    }
    __syncthreads();
    #pragma unroll
    for (int cc = 0; cc < 2; ++cc) {
        const int j = cc * 256 + tid;
        if ((j != i) && (pad[b * NSEQ + j] == 0)) {
            const int pos = s_wbase[cc * 4 + wv]
                          + __popcll(bm[cc] & ((1ull << lane) - 1ull));
            s_jlist[pos] = j;
        }
    }
    __syncthreads();
    const int M = s_M;
    // this block's contiguous half of the compacted list
    const int M2  = (M + 1) >> 1;
    const int kLo = half * M2;
    const int kHi = (half == 0) ? M2 : M;

    // ---- per-lane register state: wpr slice (h = 2*lane, 2*lane+1), pib, wp2 ----
    float wprA[R], wprB[R];
    #pragma unroll
    for (int r = 0; r < R; ++r) {
        const float2 wv2 = ((const float2*)(w_pr + r * H))[lane];
        wprA[r] = wv2.x;
        wprB[r] = wv2.y;
    }
    const float2 pib2 = ((const float2*)s_pib)[lane];
    const float2 wp22 = ((const float2*)w_p2)[lane];
    const float bp2 = b_p2[0];
    const float cix = coords[(size_t)row * 3 + 0];
    const float ciy = coords[(size_t)row * 3 + 1];
    const float ciz = coords[(size_t)row * 3 + 2];

    float cdx = 0.0f, cdy = 0.0f, cdz = 0.0f;
    float sdx = 0.0f, sdy = 0.0f, sdz = 0.0f;
    const float* pjb = pj_i + (size_t)b * NSEQ * H;
    const float gamma = 14.0625f;  // (15/4)^2

    for (int c0 = kLo; c0 < kHi; c0 += CHUNK) {
        const int cn = (kHi - c0 < CHUNK) ? (kHi - c0) : CHUNK;
        __syncthreads();
        // ---- pre-phase: this chunk's delta/rbf into LDS ----
        if (tid < cn) {
            const int k = tid;
            const int j = s_jlist[c0 + k];
            const float* cj = coords + (size_t)(b * NSEQ + j) * 3;
            const float dx = cix - cj[0];
            const float dy = ciy - cj[1];
            const float dz = ciz - cj[2];
            const float sq = dx * dx + dy * dy + dz * dz;
            const float dist = sqrtf(fmaxf(sq, 1e-12f));
            s_d4[k] = make_float4(dx, dy, dz, 0.0f);
            #pragma unroll
            for (int c = 0; c < 4; ++c) {
                float4 q;
                const float t0 = dist - (float)(4.0 * (4 * c + 0) / 15.0);
                const float t1 = dist - (float)(4.0 * (4 * c + 1) / 15.0);
                const float t2 = dist - (float)(4.0 * (4 * c + 2) / 15.0);
                const float t3 = dist - (float)(4.0 * (4 * c + 3) / 15.0);
                q.x = __expf(-gamma * t0 * t0);
                q.y = __expf(-gamma * t1 * t1);
                q.z = __expf(-gamma * t2 * t2);
                q.w = __expf(-gamma * t3 * t3);
                *(float4*)(&s_rbf[k][4 * c]) = q;
            }
        }
        __syncthreads();
        // ---- main loop: wave wv handles local k = wv, wv+4, ... within chunk ----
        for (int k = wv; k < cn; k += 4) {
            const float2 pv = ((const float2*)(pjb + (size_t)s_jlist[c0 + k] * H))[lane];
            const float4 q0 = *(const float4*)(&s_rbf[k][0]);
            const float4 q1 = *(const float4*)(&s_rbf[k][4]);
            const float4 q2 = *(const float4*)(&s_rbf[k][8]);
            const float4 q3 = *(const float4*)(&s_rbf[k][12]);
            const float4 dk = s_d4[k];

            float t0a = pib2.x + pv.x, t0b = 0.0f;
            float t1a = pib2.y + pv.y, t1b = 0.0f;
            t0a = fmaf(q0.x, wprA[0],  t0a); t0b = fmaf(q0.y, wprA[1],  t0b);
            t1a = fmaf(q0.x, wprB[0],  t1a); t1b = fmaf(q0.y, wprB[1],  t1b);
            t0a = fmaf(q0.z, wprA[2],  t0a); t0b = fmaf(q0.w, wprA[3],  t0b);
            t1a = fmaf(q0.z, wprB[2],  t1a); t1b = fmaf(q0.w, wprB[3],  t1b);
            t0a = fmaf(q1.x, wprA[4],  t0a); t0b = fmaf(q1.y, wprA[5],  t0b);
            t1a = fmaf(q1.x, wprB[4],  t1a); t1b = fmaf(q1.y, wprB[5],  t1b);
            t0a = fmaf(q1.z, wprA[6],  t0a); t0b = fmaf(q1.w, wprA[7],  t0b);
            t1a = fmaf(q1.z, wprB[6],  t1a); t1b = fmaf(q1.w, wprB[7],  t1b);
            t0a = fmaf(q2.x, wprA[8],  t0a); t0b = fmaf(q2.y, wprA[9],  t0b);
            t1a = fmaf(q2.x, wprB[8],  t1a); t1b = fmaf(q2.y, wprB[9],  t1b);
            t0a = fmaf(q2.z, wprA[10], t0a); t0b = fmaf(q2.w, wprA[11], t0b);
            t1a = fmaf(q2.z, wprB[10], t1a); t1b = fmaf(q2.w, wprB[11], t1b);
            t0a = fmaf(q3.x, wprA[12], t0a); t0b = fmaf(q3.y, wprA[13], t0b);
            t1a = fmaf(q3.x, wprB[12], t1a); t1b = fmaf(q3.y, wprB[13], t1b);
            t0a = fmaf(q3.z, wprA[14], t0a); t0b = fmaf(q3.w, wprA[15], t0b);
            t1a = fmaf(q3.z, wprB[14], t1a); t1b = fmaf(q3.w, wprB[15], t1b);
            const float u0 = fast_silu(t0a + t0b);
            const float u1 = fast_silu(t1a + t1b);
            const float part = u0 * wp22.x + u1 * wp22.y;
            cdx = fmaf(part, dk.x, cdx);
            cdy = fmaf(part, dk.y, cdy);
            cdz = fmaf(part, dk.z, cdz);
            sdx += dk.x; sdy += dk.y; sdz += dk.z;
        }
    }
    // one butterfly per wave
    #pragma unroll
    for (int off = 32; off; off >>= 1) {
        cdx += __shfl_xor(cdx, off);
        cdy += __shfl_xor(cdy, off);
        cdz += __shfl_xor(cdz, off);
    }
    if (lane == 0) {
        rw1[wv] = cdx + bp2 * sdx;
        rw2[wv] = cdy + bp2 * sdy;
        rw3[wv] = cdz + bp2 * sdz;
    }
    __syncthreads();
    if (tid == 0) {
        cd_part[row * 6 + half * 3 + 0] = rw1[0] + rw1[1] + rw1[2] + rw1[3];
        cd_part[row * 6 + half * 3 + 1] = rw2[0] + rw2[1] + rw2[2] + rw2[3];
        cd_part[row * 6 + half * 3 + 2] = rw3[0] + rw3[1] + rw3[2] + rw3[3];
    }
}

// ---------------- Kernel 3: proper jax finalize (sums the two halves) ----------------
__global__ __launch_bounds__(256) void finalize_kernel(
    const float* __restrict__ cd_part, const int* __restrict__ pad,
    float* __restrict__ out_coord)
{
    const int b = blockIdx.x;
    const int tid = threadIdx.x;
    __shared__ float r1[256], r2[256], r3[256], r4[256];
    float sx = 0.0f, sy = 0.0f, sz = 0.0f, cnt = 0.0f;
    for (int ii = tid; ii < NSEQ; ii += 256) {
        const int row = b * NSEQ + ii;
        if (pad[row] == 0) {
            sx += cd_part[row * 6 + 0] + cd_part[row * 6 + 3];
            sy += cd_part[row * 6 + 1] + cd_part[row * 6 + 4];
            sz += cd_part[row * 6 + 2] + cd_part[row * 6 + 5];
            cnt += 1.0f;
        }
    }
    r1[tid] = sx; r2[tid] = sy; r3[tid] = sz; r4[tid] = cnt;
    __syncthreads();
    for (int s = 128; s > 0; s >>= 1) {
        if (tid < s) {
            r1[tid] += r1[tid + s]; r2[tid] += r2[tid + s];
            r3[tid] += r3[tid + s]; r4[tid] += r4[tid + s];
        }
        __syncthreads();
    }
    const float denom = fmaxf(r4[0], 1.0f);
    const float inv_d = 1.0f / denom;
    const float mx = r1[0] * inv_d * inv_d;
    const float my = r2[0] * inv_d * inv_d;
    const float mz = r3[0] * inv_d * inv_d;
    for (int ii = tid; ii < NSEQ; ii += 256) {
        const int row = b * NSEQ + ii;
        const bool v = (pad[row] == 0);
        const float cx = cd_part[row * 6 + 0] + cd_part[row * 6 + 3];
        const float cy = cd_part[row * 6 + 1] + cd_part[row * 6 + 4];
        const float cz = cd_part[row * 6 + 2] + cd_part[row * 6 + 5];
        out_coord[row * 3 + 0] = v ? cx * inv_d - mx : 0.0f;
        out_coord[row * 3 + 1] = v ? cy * inv_d - my : 0.0f;
        out_coord[row * 3 + 2] = v ? cz * inv_d - mz : 0.0f;
    }
}

extern "C" void kernel_launch(void* const* d_in, const int* in_sizes, int n_in,
                              void* d_out, int out_size, void* d_ws, size_t ws_size,
                              hipStream_t stream) {
    const float* trunk  = (const float*)d_in[0];
    const float* coords = (const float*)d_in[1];
    const int*   pad    = (const int*)d_in[2];
    const float* ln_g   = (const float*)d_in[3];
    const float* ln_b   = (const float*)d_in[4];
    const float* w_a1   = (const float*)d_in[5];
    const float* b_a1   = (const float*)d_in[6];
    const float* w_a2   = (const float*)d_in[7];
    const float* b_a2   = (const float*)d_in[8];
    const float* w_pi   = (const float*)d_in[9];
    const float* w_pj   = (const float*)d_in[10];
    const float* w_pr   = (const float*)d_in[11];
    const float* b_p1   = (const float*)d_in[12];
    const float* w_p2   = (const float*)d_in[13];
    const float* b_p2   = (const float*)d_in[14];

    float* out_atom  = (float*)d_out;                 // f32 [0:10240]
    float* out_coord = out_atom + (size_t)BN * AC;    // f32 [10240:16384]

    float* cd_part = (float*)d_ws;                    // [BN][2][3] = 48 KB
    float* pj_buf  = cd_part + (size_t)BN * 6;

    row_kernel<<<BN, 256, 0, stream>>>(trunk, pad, ln_g, ln_b, w_a1, b_a1,
                                       w_a2, b_a2, w_pj, out_atom, pj_buf);
    pair_kernel<<<BN * 2, 256, 0, stream>>>(trunk, coords, pad, w_pi, w_pr, b_p1,
                                            w_p2, b_p2, pj_buf, cd_part);
    finalize_kernel<<<4, 256, 0, stream>>>(cd_part, pad, out_coord);
}

// Round 28
// 93.854 us; speedup vs baseline: 2.0945x; 1.0669x over previous
//
#include <hip/hip_runtime.h>
#include <hip/hip_bf16.h>

#define BN 2048      // B*N
#define NSEQ 512
#define D 256
#define H 128
#define R 16
#define AC 5
#define CHUNK 128

using bf16 = __hip_bfloat16;

__device__ __forceinline__ float fast_silu(float t) {
    const float e = __expf(-t);
    return t * __builtin_amdgcn_rcpf(1.0f + e);
}
__device__ __forceinline__ float bf2f(unsigned short u) {
    return __uint_as_float(((unsigned)u) << 16);
}

// ---------------- Kernel 0: per-batch valid-j compaction (includes i; diag is self-nulling) ----------------
__global__ __launch_bounds__(256) void batch_kernel(
    const int* __restrict__ pad, int* __restrict__ jlist_g, int* __restrict__ M_g)
{
    const int b = blockIdx.x;
    const int tid = threadIdx.x;
    __shared__ int s_wcnt[8];
    __shared__ int s_wbase[8];
    const int wv = tid >> 6, lane = tid & 63;
    unsigned long long bm[2];
    #pragma unroll
    for (int cc = 0; cc < 2; ++cc) {
        const int j = cc * 256 + tid;
        const int ok = (pad[b * NSEQ + j] == 0);
        bm[cc] = __ballot(ok);
        if (lane == 0) s_wcnt[cc * 4 + wv] = __popcll(bm[cc]);
    }
    __syncthreads();
    if (tid == 0) {
        int acc = 0;
        #pragma unroll
        for (int q = 0; q < 8; ++q) { s_wbase[q] = acc; acc += s_wcnt[q]; }
        M_g[b] = acc;
    }
    __syncthreads();
    #pragma unroll
    for (int cc = 0; cc < 2; ++cc) {
        const int j = cc * 256 + tid;
        if (pad[b * NSEQ + j] == 0) {
            const int pos = s_wbase[cc * 4 + wv]
                          + __popcll(bm[cc] & ((1ull << lane) - 1ull));
            jlist_g[b * NSEQ + pos] = j;
        }
    }
}

// ---------------- Kernel 1: atom head + pj + pib (pi + b_p1, bf16) ----------------
__global__ __launch_bounds__(256) void row_kernel(
    const float* __restrict__ trunk, const int* __restrict__ pad,
    const float* __restrict__ ln_g, const float* __restrict__ ln_b,
    const float* __restrict__ w_a1, const float* __restrict__ b_a1,
    const float* __restrict__ w_a2, const float* __restrict__ b_a2,
    const float* __restrict__ w_pi, const float* __restrict__ w_pj,
    const float* __restrict__ b_p1,
    float* __restrict__ out_atom, float* __restrict__ pj_o,
    unsigned short* __restrict__ pib_o)
{
    const int row = blockIdx.x;   // b*NSEQ + i
    const int tid = threadIdx.x;
    __shared__ float x[D];
    __shared__ float xn[D];
    __shared__ float y[D];
    __shared__ float r1[256];
    __shared__ float r2[256];

    const float xv = trunk[(size_t)row * D + tid];
    x[tid] = xv;
    r1[tid] = xv;
    r2[tid] = xv * xv;
    __syncthreads();
    for (int s = 128; s > 0; s >>= 1) {
        if (tid < s) { r1[tid] += r1[tid + s]; r2[tid] += r2[tid + s]; }
        __syncthreads();
    }
    const float mu   = r1[0] * (1.0f / D);
    const float var  = r2[0] * (1.0f / D) - mu * mu;
    const float rstd = rsqrtf(var + 1e-5f);
    xn[tid] = (xv - mu) * rstd * ln_g[tid] + ln_b[tid];
    __syncthreads();

    // a1 (all threads, 256-wide output)
    float acc = b_a1[tid];
    #pragma unroll 4
    for (int d = 0; d < D; ++d) acc = fmaf(xn[d], w_a1[d * D + tid], acc);
    y[tid] = acc / (1.0f + expf(-acc));   // atom path stays precise

    // balance: lower half computes pi (h=tid), upper half computes pj (h=tid-128)
    float p = 0.0f;
    if (tid < H) {
        #pragma unroll 4
        for (int d = 0; d < D; ++d) p = fmaf(x[d], w_pi[d * H + tid], p);
        p += b_p1[tid];
    } else {
        const int h = tid - H;
        #pragma unroll 4
        for (int d = 0; d < D; ++d) p = fmaf(x[d], w_pj[d * H + h], p);
    }
    __syncthreads();  // y fully written
    if (tid < H) {
        const bf16 pb = __float2bfloat16(p);
        pib_o[(size_t)row * H + tid] = *(const unsigned short*)&pb;
    } else {
        pj_o[(size_t)row * H + (tid - H)] = p;
    }

    if (tid < AC) {
        float a = b_a2[tid];
        #pragma unroll 4
        for (int d = 0; d < D; ++d) a = fmaf(y[d], w_a2[d * AC + tid], a);
        out_atom[row * AC + tid] = (pad[row] != 0) ? 0.0f : a;
    }
}

// ---------------- Kernel 2: pair head — 2-wide ILP, shared batch jlist, minimal prework ----------------
__global__ __launch_bounds__(256) void pair_kernel(
    const float* __restrict__ coords, const int* __restrict__ pad,
    const float* __restrict__ w_pr, const float* __restrict__ w_p2,
    const float* __restrict__ b_p2,
    const float* __restrict__ pj_i, const unsigned short* __restrict__ pib_i,
    const int* __restrict__ jlist_g, const int* __restrict__ M_g,
    float* __restrict__ cd_part)   // [BN][2][3]
{
    const int row  = blockIdx.x >> 1;
    const int half = blockIdx.x & 1;
    const int b = row >> 9;
    const int tid = threadIdx.x;

    if (pad[row] != 0) {
        if (tid == 0) {
            cd_part[row * 6 + half * 3 + 0] = 0.0f;
            cd_part[row * 6 + half * 3 + 1] = 0.0f;
            cd_part[row * 6 + half * 3 + 2] = 0.0f;
        }
        return;
    }

    __shared__ __align__(16) float s_rbf[CHUNK][20];  // 10 KB
    __shared__ __align__(16) float4 s_d4[CHUNK];      // 2 KB
    __shared__ int   s_jl[CHUNK];                     // 512 B
    __shared__ float rw1[4], rw2[4], rw3[4];

    const int wv = tid >> 6, lane = tid & 63;
    const int M = M_g[b];
    const int M2  = (M + 1) >> 1;
    const int kLo = half * M2;
    const int kHi = (half == 0) ? M2 : M;

    // per-lane register state
    float wprA[R], wprB[R];
    #pragma unroll
    for (int r = 0; r < R; ++r) {
        const float2 wv2 = ((const float2*)(w_pr + r * H))[lane];
        wprA[r] = wv2.x;
        wprB[r] = wv2.y;
    }
    const ushort2 pibu = ((const ushort2*)(pib_i + (size_t)row * H))[lane];
    const float pibx = bf2f(pibu.x), piby = bf2f(pibu.y);
    const float2 wp22 = ((const float2*)w_p2)[lane];
    const float bp2 = b_p2[0];
    const float cix = coords[(size_t)row * 3 + 0];
    const float ciy = coords[(size_t)row * 3 + 1];
    const float ciz = coords[(size_t)row * 3 + 2];

    float cdx = 0.0f, cdy = 0.0f, cdz = 0.0f;
    float sdx = 0.0f, sdy = 0.0f, sdz = 0.0f;
    const float* pjb = pj_i + (size_t)b * NSEQ * H;
    const float gamma = 14.0625f;  // (15/4)^2

    for (int c0 = kLo; c0 < kHi; c0 += CHUNK) {
        const int cn = (kHi - c0 < CHUNK) ? (kHi - c0) : CHUNK;
        __syncthreads();
        // stage chunk: indices + delta/rbf
        if (tid < cn) {
            const int j = jlist_g[b * NSEQ + c0 + tid];
            s_jl[tid] = j;
            const float* cj = coords + (size_t)(b * NSEQ + j) * 3;
            const float dx = cix - cj[0];
            const float dy = ciy - cj[1];
            const float dz = ciz - cj[2];
            const float sq = dx * dx + dy * dy + dz * dz;
            const float dist = sqrtf(fmaxf(sq, 1e-12f));
            s_d4[tid] = make_float4(dx, dy, dz, 0.0f);
            #pragma unroll
            for (int c = 0; c < 4; ++c) {
                float4 q;
                const float t0 = dist - (float)(4.0 * (4 * c + 0) / 15.0);
                const float t1 = dist - (float)(4.0 * (4 * c + 1) / 15.0);
                const float t2 = dist - (float)(4.0 * (4 * c + 2) / 15.0);
                const float t3 = dist - (float)(4.0 * (4 * c + 3) / 15.0);
                q.x = __expf(-gamma * t0 * t0);
                q.y = __expf(-gamma * t1 * t1);
                q.z = __expf(-gamma * t2 * t2);
                q.w = __expf(-gamma * t3 * t3);
                *(float4*)(&s_rbf[tid][4 * c]) = q;
            }
        }
        __syncthreads();
        // main loop: wave wv handles k and k+4 per iteration (2 loads in flight)
        for (int k = wv; k < cn; k += 8) {
            const int kB = k + 4;
            const bool have2 = (kB < cn);          // wave-uniform
            const int jA = s_jl[k];
            const int jB = s_jl[have2 ? kB : k];
            const float2 pvA = ((const float2*)(pjb + (size_t)jA * H))[lane];
            const float2 pvB = ((const float2*)(pjb + (size_t)jB * H))[lane];

            {   // pair A
                const float4 q0 = *(const float4*)(&s_rbf[k][0]);
                const float4 q1 = *(const float4*)(&s_rbf[k][4]);
                const float4 q2 = *(const float4*)(&s_rbf[k][8]);
                const float4 q3 = *(const float4*)(&s_rbf[k][12]);
                const float4 dk = s_d4[k];
                float t0a = pibx + pvA.x, t0b = 0.0f;
                float t1a = piby + pvA.y, t1b = 0.0f;
                t0a = fmaf(q0.x, wprA[0],  t0a); t0b = fmaf(q0.y, wprA[1],  t0b);
                t1a = fmaf(q0.x, wprB[0],  t1a); t1b = fmaf(q0.y, wprB[1],  t1b);
                t0a = fmaf(q0.z, wprA[2],  t0a); t0b = fmaf(q0.w, wprA[3],  t0b);
                t1a = fmaf(q0.z, wprB[2],  t1a); t1b = fmaf(q0.w, wprB[3],  t1b);
                t0a = fmaf(q1.x, wprA[4],  t0a); t0b = fmaf(q1.y, wprA[5],  t0b);
                t1a = fmaf(q1.x, wprB[4],  t1a); t1b = fmaf(q1.y, wprB[5],  t1b);
                t0a = fmaf(q1.z, wprA[6],  t0a); t0b = fmaf(q1.w, wprA[7],  t0b);
                t1a = fmaf(q1.z, wprB[6],  t1a); t1b = fmaf(q1.w, wprB[7],  t1b);
                t0a = fmaf(q2.x, wprA[8],  t0a); t0b = fmaf(q2.y, wprA[9],  t0b);
                t1a = fmaf(q2.x, wprB[8],  t1a); t1b = fmaf(q2.y, wprB[9],  t1b);
                t0a = fmaf(q2.z, wprA[10], t0a); t0b = fmaf(q2.w, wprA[11], t0b);
                t1a = fmaf(q2.z, wprB[10], t1a); t1b = fmaf(q2.w, wprB[11], t1b);
                t0a = fmaf(q3.x, wprA[12], t0a); t0b = fmaf(q3.y, wprA[13], t0b);
                t1a = fmaf(q3.x, wprB[12], t1a); t1b = fmaf(q3.y, wprB[13], t1b);
                t0a = fmaf(q3.z, wprA[14], t0a); t0b = fmaf(q3.w, wprA[15], t0b);
                t1a = fmaf(q3.z, wprB[14], t1a); t1b = fmaf(q3.w, wprB[15], t1b);
                const float u0 = fast_silu(t0a + t0b);
                const float u1 = fast_silu(t1a + t1b);
                const float part = u0 * wp22.x + u1 * wp22.y;
                cdx = fmaf(part, dk.x, cdx);
                cdy = fmaf(part, dk.y, cdy);
                cdz = fmaf(part, dk.z, cdz);
                sdx += dk.x; sdy += dk.y; sdz += dk.z;
            }
            if (have2) {   // pair B
                const float4 q0 = *(const float4*)(&s_rbf[kB][0]);
                const float4 q1 = *(const float4*)(&s_rbf[kB][4]);
                const float4 q2 = *(const float4*)(&s_rbf[kB][8]);
                const float4 q3 = *(const float4*)(&s_rbf[kB][12]);
                const float4 dk = s_d4[kB];
                float t0a = pibx + pvB.x, t0b = 0.0f;
                float t1a = piby + pvB.y, t1b = 0.0f;
                t0a = fmaf(q0.x, wprA[0],  t0a); t0b = fmaf(q0.y, wprA[1],  t0b);
                t1a = fmaf(q0.x, wprB[0],  t1a); t1b = fmaf(q0.y, wprB[1],  t1b);
                t0a = fmaf(q0.z, wprA[2],  t0a); t0b = fmaf(q0.w, wprA[3],  t0b);
                t1a = fmaf(q0.z, wprB[2],  t1a); t1b = fmaf(q0.w, wprB[3],  t1b);
                t0a = fmaf(q1.x, wprA[4],  t0a); t0b = fmaf(q1.y, wprA[5],  t0b);
                t1a = fmaf(q1.x, wprB[4],  t1a); t1b = fmaf(q1.y, wprB[5],  t1b);
                t0a = fmaf(q1.z, wprA[6],  t0a); t0b = fmaf(q1.w, wprA[7],  t0b);
                t1a = fmaf(q1.z, wprB[6],  t1a); t1b = fmaf(q1.w, wprB[7],  t1b);
                t0a = fmaf(q2.x, wprA[8],  t0a); t0b = fmaf(q2.y, wprA[9],  t0b);
                t1a = fmaf(q2.x, wprB[8],  t1a); t1b = fmaf(q2.y, wprB[9],  t1b);
                t0a = fmaf(q2.z, wprA[10], t0a); t0b = fmaf(q2.w, wprA[11], t0b);
                t1a = fmaf(q2.z, wprB[10], t1a); t1b = fmaf(q2.w, wprB[11], t1b);
                t0a = fmaf(q3.x, wprA[12], t0a); t0b = fmaf(q3.y, wprA[13], t0b);
                t1a = fmaf(q3.x, wprB[12], t1a); t1b = fmaf(q3.y, wprB[13], t1b);
                t0a = fmaf(q3.z, wprA[14], t0a); t0b = fmaf(q3.w, wprA[15], t0b);
                t1a = fmaf(q3.z, wprB[14], t1a); t1b = fmaf(q3.w, wprB[15], t1b);
                const float u0 = fast_silu(t0a + t0b);
                const float u1 = fast_silu(t1a + t1b);
                const float part = u0 * wp22.x + u1 * wp22.y;
                cdx = fmaf(part, dk.x, cdx);
                cdy = fmaf(part, dk.y, cdy);
                cdz = fmaf(part, dk.z, cdz);
                sdx += dk.x; sdy += dk.y; sdz += dk.z;
            }
        }
    }
    // one butterfly per wave
    #pragma unroll
    for (int off = 32; off; off >>= 1) {
        cdx += __shfl_xor(cdx, off);
        cdy += __shfl_xor(cdy, off);
        cdz += __shfl_xor(cdz, off);
    }
    if (lane == 0) {
        rw1[wv] = cdx + bp2 * sdx;
        rw2[wv] = cdy + bp2 * sdy;
        rw3[wv] = cdz + bp2 * sdz;
    }
    __syncthreads();
    if (tid == 0) {
        cd_part[row * 6 + half * 3 + 0] = rw1[0] + rw1[1] + rw1[2] + rw1[3];
        cd_part[row * 6 + half * 3 + 1] = rw2[0] + rw2[1] + rw2[2] + rw2[3];
        cd_part[row * 6 + half * 3 + 2] = rw3[0] + rw3[1] + rw3[2] + rw3[3];
    }
}

// ---------------- Kernel 3: proper jax finalize (sums the two halves) ----------------
__global__ __launch_bounds__(256) void finalize_kernel(
    const float* __restrict__ cd_part, const int* __restrict__ pad,
    float* __restrict__ out_coord)
{
    const int b = blockIdx.x;
    const int tid = threadIdx.x;
    __shared__ float r1[256], r2[256], r3[256], r4[256];
    float sx = 0.0f, sy = 0.0f, sz = 0.0f, cnt = 0.0f;
    for (int ii = tid; ii < NSEQ; ii += 256) {
        const int row = b * NSEQ + ii;
        if (pad[row] == 0) {
            sx += cd_part[row * 6 + 0] + cd_part[row * 6 + 3];
            sy += cd_part[row * 6 + 1] + cd_part[row * 6 + 4];
            sz += cd_part[row * 6 + 2] + cd_part[row * 6 + 5];
            cnt += 1.0f;
        }
    }
    r1[tid] = sx; r2[tid] = sy; r3[tid] = sz; r4[tid] = cnt;
    __syncthreads();
    for (int s = 128; s > 0; s >>= 1) {
        if (tid < s) {
            r1[tid] += r1[tid + s]; r2[tid] += r2[tid + s];
            r3[tid] += r3[tid + s]; r4[tid] += r4[tid + s];
        }
        __syncthreads();
    }
    const float denom = fmaxf(r4[0], 1.0f);
    const float inv_d = 1.0f / denom;
    const float mx = r1[0] * inv_d * inv_d;
    const float my = r2[0] * inv_d * inv_d;
    const float mz = r3[0] * inv_d * inv_d;
    for (int ii = tid; ii < NSEQ; ii += 256) {
        const int row = b * NSEQ + ii;
        const bool v = (pad[row] == 0);
        const float cx = cd_part[row * 6 + 0] + cd_part[row * 6 + 3];
        const float cy = cd_part[row * 6 + 1] + cd_part[row * 6 + 4];
        const float cz = cd_part[row * 6 + 2] + cd_part[row * 6 + 5];
        out_coord[row * 3 + 0] = v ? cx * inv_d - mx : 0.0f;
        out_coord[row * 3 + 1] = v ? cy * inv_d - my : 0.0f;
        out_coord[row * 3 + 2] = v ? cz * inv_d - mz : 0.0f;
    }
}

extern "C" void kernel_launch(void* const* d_in, const int* in_sizes, int n_in,
                              void* d_out, int out_size, void* d_ws, size_t ws_size,
                              hipStream_t stream) {
    const float* trunk  = (const float*)d_in[0];
    const float* coords = (const float*)d_in[1];
    const int*   pad    = (const int*)d_in[2];
    const float* ln_g   = (const float*)d_in[3];
    const float* ln_b   = (const float*)d_in[4];
    const float* w_a1   = (const float*)d_in[5];
    const float* b_a1   = (const float*)d_in[6];
    const float* w_a2   = (const float*)d_in[7];
    const float* b_a2   = (const float*)d_in[8];
    const float* w_pi   = (const float*)d_in[9];
    const float* w_pj   = (const float*)d_in[10];
    const float* w_pr   = (const float*)d_in[11];
    const float* b_p1   = (const float*)d_in[12];
    const float* w_p2   = (const float*)d_in[13];
    const float* b_p2   = (const float*)d_in[14];

    float* out_atom  = (float*)d_out;                 // f32 [0:10240]
    float* out_coord = out_atom + (size_t)BN * AC;    // f32 [10240:16384]

    // ws layout (~1.63 MB): jlist[4*512] M[4] | cd_part[BN*6] | pj f32[BN*H] | pib bf16[BN*H]
    int*   jlist_g = (int*)d_ws;
    int*   M_g     = jlist_g + 4 * NSEQ;
    float* cd_part = (float*)(M_g + 16);              // padded
    float* pj_buf  = cd_part + (size_t)BN * 6;
    unsigned short* pib_buf = (unsigned short*)(pj_buf + (size_t)BN * H);

    batch_kernel<<<4, 256, 0, stream>>>(pad, jlist_g, M_g);
    row_kernel<<<BN, 256, 0, stream>>>(trunk, pad, ln_g, ln_b, w_a1, b_a1,
                                       w_a2, b_a2, w_pi, w_pj, b_p1,
                                       out_atom, pj_buf, pib_buf);
    pair_kernel<<<BN * 2, 256, 0, stream>>>(coords, pad, w_pr, w_p2, b_p2,
                                            pj_buf, pib_buf, jlist_g, M_g, cd_part);
    finalize_kernel<<<4, 256, 0, stream>>>(cd_part, pad, out_coord);
}

// Round 29
// 70.145 us; speedup vs baseline: 2.8024x; 1.3380x over previous
//
#include <hip/hip_runtime.h>
#include <hip/hip_bf16.h>

#define BN 2048      // B*N
#define NSEQ 512
#define D 256
#define H 128
#define R 16
#define AC 5
#define CHUNK 128
#define ROWG 4

using bf16 = __hip_bfloat16;

__device__ __forceinline__ float fast_silu(float t) {
    const float e = __expf(-t);
    return t * __builtin_amdgcn_rcpf(1.0f + e);
}
__device__ __forceinline__ float bf2f(unsigned short u) {
    return __uint_as_float(((unsigned)u) << 16);
}

// ---------------- Kernel 0: per-batch valid-j compaction (includes i; diag self-nulls) ----------------
__global__ __launch_bounds__(256) void batch_kernel(
    const int* __restrict__ pad, int* __restrict__ jlist_g, int* __restrict__ M_g)
{
    const int b = blockIdx.x;
    const int tid = threadIdx.x;
    __shared__ int s_wcnt[8];
    __shared__ int s_wbase[8];
    const int wv = tid >> 6, lane = tid & 63;
    unsigned long long bm[2];
    #pragma unroll
    for (int cc = 0; cc < 2; ++cc) {
        const int j = cc * 256 + tid;
        const int ok = (pad[b * NSEQ + j] == 0);
        bm[cc] = __ballot(ok);
        if (lane == 0) s_wcnt[cc * 4 + wv] = __popcll(bm[cc]);
    }
    __syncthreads();
    if (tid == 0) {
        int acc = 0;
        #pragma unroll
        for (int q = 0; q < 8; ++q) { s_wbase[q] = acc; acc += s_wcnt[q]; }
        M_g[b] = acc;
    }
    __syncthreads();
    #pragma unroll
    for (int cc = 0; cc < 2; ++cc) {
        const int j = cc * 256 + tid;
        if (pad[b * NSEQ + j] == 0) {
            const int pos = s_wbase[cc * 4 + wv]
                          + __popcll(bm[cc] & ((1ull << lane) - 1ull));
            jlist_g[b * NSEQ + pos] = j;
        }
    }
}

// ---------------- Kernel 1: atom head + pj + pib, ROWG=4 rows/block (weight reuse) ----------------
__global__ __launch_bounds__(256) void row_kernel(
    const float* __restrict__ trunk, const int* __restrict__ pad,
    const float* __restrict__ ln_g, const float* __restrict__ ln_b,
    const float* __restrict__ w_a1, const float* __restrict__ b_a1,
    const float* __restrict__ w_a2, const float* __restrict__ b_a2,
    const float* __restrict__ w_pi, const float* __restrict__ w_pj,
    const float* __restrict__ b_p1,
    float* __restrict__ out_atom, float* __restrict__ pj_o,
    unsigned short* __restrict__ pib_o)
{
    const int row0 = blockIdx.x * ROWG;
    const int tid = threadIdx.x;
    const int wv = tid >> 6, lane = tid & 63;
    __shared__ __align__(16) float x_t[D][ROWG];    // transposed: one float4 = 4 rows
    __shared__ __align__(16) float xn_t[D][ROWG];
    __shared__ float y[ROWG][D];
    __shared__ float mu_s[ROWG], rs_s[ROWG];

    // load 4 rows (coalesced), store transposed
    #pragma unroll
    for (int g = 0; g < ROWG; ++g)
        x_t[tid][g] = trunk[(size_t)(row0 + g) * D + tid];
    __syncthreads();

    // wave wv computes LN stats for row wv via shuffle reduction
    {
        const int g = wv;
        float s = 0.0f, ss = 0.0f;
        #pragma unroll
        for (int e = lane; e < D; e += 64) {
            const float v = x_t[e][g];
            s += v; ss += v * v;
        }
        #pragma unroll
        for (int off = 32; off; off >>= 1) {
            s  += __shfl_xor(s, off);
            ss += __shfl_xor(ss, off);
        }
        if (lane == 0) {
            const float mu  = s * (1.0f / D);
            const float var = ss * (1.0f / D) - mu * mu;
            mu_s[g] = mu;
            rs_s[g] = rsqrtf(var + 1e-5f);
        }
    }
    __syncthreads();
    {
        const float lg = ln_g[tid], lb = ln_b[tid];
        #pragma unroll
        for (int g = 0; g < ROWG; ++g)
            xn_t[tid][g] = (x_t[tid][g] - mu_s[g]) * rs_s[g] * lg + lb;
    }
    __syncthreads();

    // a1 GEMM: 1 weight load feeds 4 FMAs
    {
        float acc0 = b_a1[tid], acc1 = acc0, acc2 = acc0, acc3 = acc0;
        for (int d = 0; d < D; ++d) {
            const float w = w_a1[d * D + tid];
            const float4 xv = *(const float4*)xn_t[d];   // broadcast
            acc0 = fmaf(xv.x, w, acc0);
            acc1 = fmaf(xv.y, w, acc1);
            acc2 = fmaf(xv.z, w, acc2);
            acc3 = fmaf(xv.w, w, acc3);
        }
        y[0][tid] = acc0 / (1.0f + expf(-acc0));
        y[1][tid] = acc1 / (1.0f + expf(-acc1));
        y[2][tid] = acc2 / (1.0f + expf(-acc2));
        y[3][tid] = acc3 / (1.0f + expf(-acc3));
    }

    // pi (tid<H) / pj (tid>=H) for all 4 rows
    float p0 = 0.0f, p1 = 0.0f, p2 = 0.0f, p3 = 0.0f;
    if (tid < H) {
        for (int d = 0; d < D; ++d) {
            const float w = w_pi[d * H + tid];
            const float4 xv = *(const float4*)x_t[d];
            p0 = fmaf(xv.x, w, p0);
            p1 = fmaf(xv.y, w, p1);
            p2 = fmaf(xv.z, w, p2);
            p3 = fmaf(xv.w, w, p3);
        }
        const float bb = b_p1[tid];
        p0 += bb; p1 += bb; p2 += bb; p3 += bb;
    } else {
        const int h = tid - H;
        for (int d = 0; d < D; ++d) {
            const float w = w_pj[d * H + h];
            const float4 xv = *(const float4*)x_t[d];
            p0 = fmaf(xv.x, w, p0);
            p1 = fmaf(xv.y, w, p1);
            p2 = fmaf(xv.z, w, p2);
            p3 = fmaf(xv.w, w, p3);
        }
    }
    __syncthreads();   // y fully written
    if (tid < H) {
        const float pv[ROWG] = {p0, p1, p2, p3};
        #pragma unroll
        for (int g = 0; g < ROWG; ++g) {
            const bf16 pb = __float2bfloat16(pv[g]);
            pib_o[(size_t)(row0 + g) * H + tid] = *(const unsigned short*)&pb;
        }
    } else {
        const int h = tid - H;
        const float pv[ROWG] = {p0, p1, p2, p3};
        #pragma unroll
        for (int g = 0; g < ROWG; ++g)
            pj_o[(size_t)(row0 + g) * H + h] = pv[g];
    }

    // a2: 20 threads, (g = tid/AC, c = tid%AC)
    if (tid < ROWG * AC) {
        const int g = tid / AC, c = tid % AC;
        float a = b_a2[c];
        for (int d = 0; d < D; ++d) a = fmaf(y[g][d], w_a2[d * AC + c], a);
        out_atom[(row0 + g) * AC + c] = (pad[row0 + g] != 0) ? 0.0f : a;
    }
}

// ---------------- Kernel 2: pair head — 2-wide ILP, shared batch jlist (unchanged, passes) ----------------
__global__ __launch_bounds__(256) void pair_kernel(
    const float* __restrict__ coords, const int* __restrict__ pad,
    const float* __restrict__ w_pr, const float* __restrict__ w_p2,
    const float* __restrict__ b_p2,
    const float* __restrict__ pj_i, const unsigned short* __restrict__ pib_i,
    const int* __restrict__ jlist_g, const int* __restrict__ M_g,
    float* __restrict__ cd_part)   // [BN][2][3]
{
    const int row  = blockIdx.x >> 1;
    const int half = blockIdx.x & 1;
    const int b = row >> 9;
    const int tid = threadIdx.x;

    if (pad[row] != 0) {
        if (tid == 0) {
            cd_part[row * 6 + half * 3 + 0] = 0.0f;
            cd_part[row * 6 + half * 3 + 1] = 0.0f;
            cd_part[row * 6 + half * 3 + 2] = 0.0f;
        }
        return;
    }

    __shared__ __align__(16) float s_rbf[CHUNK][20];
    __shared__ __align__(16) float4 s_d4[CHUNK];
    __shared__ int   s_jl[CHUNK];
    __shared__ float rw1[4], rw2[4], rw3[4];

    const int wv = tid >> 6, lane = tid & 63;
    const int M = M_g[b];
    const int M2  = (M + 1) >> 1;
    const int kLo = half * M2;
    const int kHi = (half == 0) ? M2 : M;

    float wprA[R], wprB[R];
    #pragma unroll
    for (int r = 0; r < R; ++r) {
        const float2 wv2 = ((const float2*)(w_pr + r * H))[lane];
        wprA[r] = wv2.x;
        wprB[r] = wv2.y;
    }
    const ushort2 pibu = ((const ushort2*)(pib_i + (size_t)row * H))[lane];
    const float pibx = bf2f(pibu.x), piby = bf2f(pibu.y);
    const float2 wp22 = ((const float2*)w_p2)[lane];
    const float bp2 = b_p2[0];
    const float cix = coords[(size_t)row * 3 + 0];
    const float ciy = coords[(size_t)row * 3 + 1];
    const float ciz = coords[(size_t)row * 3 + 2];

    float cdx = 0.0f, cdy = 0.0f, cdz = 0.0f;
    float sdx = 0.0f, sdy = 0.0f, sdz = 0.0f;
    const float* pjb = pj_i + (size_t)b * NSEQ * H;
    const float gamma = 14.0625f;  // (15/4)^2

    for (int c0 = kLo; c0 < kHi; c0 += CHUNK) {
        const int cn = (kHi - c0 < CHUNK) ? (kHi - c0) : CHUNK;
        __syncthreads();
        if (tid < cn) {
            const int j = jlist_g[b * NSEQ + c0 + tid];
            s_jl[tid] = j;
            const float* cj = coords + (size_t)(b * NSEQ + j) * 3;
            const float dx = cix - cj[0];
            const float dy = ciy - cj[1];
            const float dz = ciz - cj[2];
            const float sq = dx * dx + dy * dy + dz * dz;
            const float dist = sqrtf(fmaxf(sq, 1e-12f));
            s_d4[tid] = make_float4(dx, dy, dz, 0.0f);
            #pragma unroll
            for (int c = 0; c < 4; ++c) {
                float4 q;
                const float t0 = dist - (float)(4.0 * (4 * c + 0) / 15.0);
                const float t1 = dist - (float)(4.0 * (4 * c + 1) / 15.0);
                const float t2 = dist - (float)(4.0 * (4 * c + 2) / 15.0);
                const float t3 = dist - (float)(4.0 * (4 * c + 3) / 15.0);
                q.x = __expf(-gamma * t0 * t0);
                q.y = __expf(-gamma * t1 * t1);
                q.z = __expf(-gamma * t2 * t2);
                q.w = __expf(-gamma * t3 * t3);
                *(float4*)(&s_rbf[tid][4 * c]) = q;
            }
        }
        __syncthreads();
        for (int k = wv; k < cn; k += 8) {
            const int kB = k + 4;
            const bool have2 = (kB < cn);
            const int jA = s_jl[k];
            const int jB = s_jl[have2 ? kB : k];
            const float2 pvA = ((const float2*)(pjb + (size_t)jA * H))[lane];
            const float2 pvB = ((const float2*)(pjb + (size_t)jB * H))[lane];

            {
                const float4 q0 = *(const float4*)(&s_rbf[k][0]);
                const float4 q1 = *(const float4*)(&s_rbf[k][4]);
                const float4 q2 = *(const float4*)(&s_rbf[k][8]);
                const float4 q3 = *(const float4*)(&s_rbf[k][12]);
                const float4 dk = s_d4[k];
                float t0a = pibx + pvA.x, t0b = 0.0f;
                float t1a = piby + pvA.y, t1b = 0.0f;
                t0a = fmaf(q0.x, wprA[0],  t0a); t0b = fmaf(q0.y, wprA[1],  t0b);
                t1a = fmaf(q0.x, wprB[0],  t1a); t1b = fmaf(q0.y, wprB[1],  t1b);
                t0a = fmaf(q0.z, wprA[2],  t0a); t0b = fmaf(q0.w, wprA[3],  t0b);
                t1a = fmaf(q0.z, wprB[2],  t1a); t1b = fmaf(q0.w, wprB[3],  t1b);
                t0a = fmaf(q1.x, wprA[4],  t0a); t0b = fmaf(q1.y, wprA[5],  t0b);
                t1a = fmaf(q1.x, wprB[4],  t1a); t1b = fmaf(q1.y, wprB[5],  t1b);
                t0a = fmaf(q1.z, wprA[6],  t0a); t0b = fmaf(q1.w, wprA[7],  t0b);
                t1a = fmaf(q1.z, wprB[6],  t1a); t1b = fmaf(q1.w, wprB[7],  t1b);
                t0a = fmaf(q2.x, wprA[8],  t0a); t0b = fmaf(q2.y, wprA[9],  t0b);
                t1a = fmaf(q2.x, wprB[8],  t1a); t1b = fmaf(q2.y, wprB[9],  t1b);
                t0a = fmaf(q2.z, wprA[10], t0a); t0b = fmaf(q2.w, wprA[11], t0b);
                t1a = fmaf(q2.z, wprB[10], t1a); t1b = fmaf(q2.w, wprB[11], t1b);
                t0a = fmaf(q3.x, wprA[12], t0a); t0b = fmaf(q3.y, wprA[13], t0b);
                t1a = fmaf(q3.x, wprB[12], t1a); t1b = fmaf(q3.y, wprB[13], t1b);
                t0a = fmaf(q3.z, wprA[14], t0a); t0b = fmaf(q3.w, wprA[15], t0b);
                t1a = fmaf(q3.z, wprB[14], t1a); t1b = fmaf(q3.w, wprB[15], t1b);
                const float u0 = fast_silu(t0a + t0b);
                const float u1 = fast_silu(t1a + t1b);
                const float part = u0 * wp22.x + u1 * wp22.y;
                cdx = fmaf(part, dk.x, cdx);
                cdy = fmaf(part, dk.y, cdy);
                cdz = fmaf(part, dk.z, cdz);
                sdx += dk.x; sdy += dk.y; sdz += dk.z;
            }
            if (have2) {
                const float4 q0 = *(const float4*)(&s_rbf[kB][0]);
                const float4 q1 = *(const float4*)(&s_rbf[kB][4]);
                const float4 q2 = *(const float4*)(&s_rbf[kB][8]);
                const float4 q3 = *(const float4*)(&s_rbf[kB][12]);
                const float4 dk = s_d4[kB];
                float t0a = pibx + pvB.x, t0b = 0.0f;
                float t1a = piby + pvB.y, t1b = 0.0f;
                t0a = fmaf(q0.x, wprA[0],  t0a); t0b = fmaf(q0.y, wprA[1],  t0b);
                t1a = fmaf(q0.x, wprB[0],  t1a); t1b = fmaf(q0.y, wprB[1],  t1b);
                t0a = fmaf(q0.z, wprA[2],  t0a); t0b = fmaf(q0.w, wprA[3],  t0b);
                t1a = fmaf(q0.z, wprB[2],  t1a); t1b = fmaf(q0.w, wprB[3],  t1b);
                t0a = fmaf(q1.x, wprA[4],  t0a); t0b = fmaf(q1.y, wprA[5],  t0b);
                t1a = fmaf(q1.x, wprB[4],  t1a); t1b = fmaf(q1.y, wprB[5],  t1b);
                t0a = fmaf(q1.z, wprA[6],  t0a); t0b = fmaf(q1.w, wprA[7],  t0b);
                t1a = fmaf(q1.z, wprB[6],  t1a); t1b = fmaf(q1.w, wprB[7],  t1b);
                t0a = fmaf(q2.x, wprA[8],  t0a); t0b = fmaf(q2.y, wprA[9],  t0b);
                t1a = fmaf(q2.x, wprB[8],  t1a); t1b = fmaf(q2.y, wprB[9],  t1b);
                t0a = fmaf(q2.z, wprA[10], t0a); t0b = fmaf(q2.w, wprA[11], t0b);
                t1a = fmaf(q2.z, wprB[10], t1a); t1b = fmaf(q2.w, wprB[11], t1b);
                t0a = fmaf(q3.x, wprA[12], t0a); t0b = fmaf(q3.y, wprA[13], t0b);
                t1a = fmaf(q3.x, wprB[12], t1a); t1b = fmaf(q3.y, wprB[13], t1b);
                t0a = fmaf(q3.z, wprA[14], t0a); t0b = fmaf(q3.w, wprA[15], t0b);
                t1a = fmaf(q3.z, wprB[14], t1a); t1b = fmaf(q3.w, wprB[15], t1b);
                const float u0 = fast_silu(t0a + t0b);
                const float u1 = fast_silu(t1a + t1b);
                const float part = u0 * wp22.x + u1 * wp22.y;
                cdx = fmaf(part, dk.x, cdx);
                cdy = fmaf(part, dk.y, cdy);
                cdz = fmaf(part, dk.z, cdz);
                sdx += dk.x; sdy += dk.y; sdz += dk.z;
            }
        }
    }
    #pragma unroll
    for (int off = 32; off; off >>= 1) {
        cdx += __shfl_xor(cdx, off);
        cdy += __shfl_xor(cdy, off);
        cdz += __shfl_xor(cdz, off);
    }
    if (lane == 0) {
        rw1[wv] = cdx + bp2 * sdx;
        rw2[wv] = cdy + bp2 * sdy;
        rw3[wv] = cdz + bp2 * sdz;
    }
    __syncthreads();
    if (tid == 0) {
        cd_part[row * 6 + half * 3 + 0] = rw1[0] + rw1[1] + rw1[2] + rw1[3];
        cd_part[row * 6 + half * 3 + 1] = rw2[0] + rw2[1] + rw2[2] + rw2[3];
        cd_part[row * 6 + half * 3 + 2] = rw3[0] + rw3[1] + rw3[2] + rw3[3];
    }
}

// ---------------- Kernel 3: proper jax finalize (sums the two halves) ----------------
__global__ __launch_bounds__(256) void finalize_kernel(
    const float* __restrict__ cd_part, const int* __restrict__ pad,
    float* __restrict__ out_coord)
{
    const int b = blockIdx.x;
    const int tid = threadIdx.x;
    __shared__ float r1[256], r2[256], r3[256], r4[256];
    float sx = 0.0f, sy = 0.0f, sz = 0.0f, cnt = 0.0f;
    for (int ii = tid; ii < NSEQ; ii += 256) {
        const int row = b * NSEQ + ii;
        if (pad[row] == 0) {
            sx += cd_part[row * 6 + 0] + cd_part[row * 6 + 3];
            sy += cd_part[row * 6 + 1] + cd_part[row * 6 + 4];
            sz += cd_part[row * 6 + 2] + cd_part[row * 6 + 5];
            cnt += 1.0f;
        }
    }
    r1[tid] = sx; r2[tid] = sy; r3[tid] = sz; r4[tid] = cnt;
    __syncthreads();
    for (int s = 128; s > 0; s >>= 1) {
        if (tid < s) {
            r1[tid] += r1[tid + s]; r2[tid] += r2[tid + s];
            r3[tid] += r3[tid + s]; r4[tid] += r4[tid + s];
        }
        __syncthreads();
    }
    const float denom = fmaxf(r4[0], 1.0f);
    const float inv_d = 1.0f / denom;
    const float mx = r1[0] * inv_d * inv_d;
    const float my = r2[0] * inv_d * inv_d;
    const float mz = r3[0] * inv_d * inv_d;
    for (int ii = tid; ii < NSEQ; ii += 256) {
        const int row = b * NSEQ + ii;
        const bool v = (pad[row] == 0);
        const float cx = cd_part[row * 6 + 0] + cd_part[row * 6 + 3];
        const float cy = cd_part[row * 6 + 1] + cd_part[row * 6 + 4];
        const float cz = cd_part[row * 6 + 2] + cd_part[row * 6 + 5];
        out_coord[row * 3 + 0] = v ? cx * inv_d - mx : 0.0f;
        out_coord[row * 3 + 1] = v ? cy * inv_d - my : 0.0f;
        out_coord[row * 3 + 2] = v ? cz * inv_d - mz : 0.0f;
    }
}

extern "C" void kernel_launch(void* const* d_in, const int* in_sizes, int n_in,
                              void* d_out, int out_size, void* d_ws, size_t ws_size,
                              hipStream_t stream) {
    const float* trunk  = (const float*)d_in[0];
    const float* coords = (const float*)d_in[1];
    const int*   pad    = (const int*)d_in[2];
    const float* ln_g   = (const float*)d_in[3];
    const float* ln_b   = (const float*)d_in[4];
    const float* w_a1   = (const float*)d_in[5];
    const float* b_a1   = (const float*)d_in[6];
    const float* w_a2   = (const float*)d_in[7];
    const float* b_a2   = (const float*)d_in[8];
    const float* w_pi   = (const float*)d_in[9];
    const float* w_pj   = (const float*)d_in[10];
    const float* w_pr   = (const float*)d_in[11];
    const float* b_p1   = (const float*)d_in[12];
    const float* w_p2   = (const float*)d_in[13];
    const float* b_p2   = (const float*)d_in[14];

    float* out_atom  = (float*)d_out;                 // f32 [0:10240]
    float* out_coord = out_atom + (size_t)BN * AC;    // f32 [10240:16384]

    // ws layout: jlist[4*512] M[16] | cd_part[BN*6] | pj f32[BN*H] | pib bf16[BN*H]
    int*   jlist_g = (int*)d_ws;
    int*   M_g     = jlist_g + 4 * NSEQ;
    float* cd_part = (float*)(M_g + 16);
    float* pj_buf  = cd_part + (size_t)BN * 6;
    unsigned short* pib_buf = (unsigned short*)(pj_buf + (size_t)BN * H);

    batch_kernel<<<4, 256, 0, stream>>>(pad, jlist_g, M_g);
    row_kernel<<<BN / ROWG, 256, 0, stream>>>(trunk, pad, ln_g, ln_b, w_a1, b_a1,
                                              w_a2, b_a2, w_pi, w_pj, b_p1,
                                              out_atom, pj_buf, pib_buf);
    pair_kernel<<<BN * 2, 256, 0, stream>>>(coords, pad, w_pr, w_p2, b_p2,
                                            pj_buf, pib_buf, jlist_g, M_g, cd_part);
    finalize_kernel<<<4, 256, 0, stream>>>(cd_part, pad, out_coord);
}

// Round 30
// 69.633 us; speedup vs baseline: 2.8230x; 1.0074x over previous
//
#include <hip/hip_runtime.h>
#include <hip/hip_bf16.h>

#define BN 2048      // B*N
#define NSEQ 512
#define D 256
#define H 128
#define R 16
#define AC 5
#define CHUNK 128
#define ROWG 4
#define SPLIT 4

using bf16 = __hip_bfloat16;

__device__ __forceinline__ float fast_silu(float t) {
    const float e = __expf(-t);
    return t * __builtin_amdgcn_rcpf(1.0f + e);
}
__device__ __forceinline__ float bf2f(unsigned short u) {
    return __uint_as_float(((unsigned)u) << 16);
}

// ---------------- Kernel 0: per-batch valid-j compaction (includes i; diag self-nulls) ----------------
__global__ __launch_bounds__(256) void batch_kernel(
    const int* __restrict__ pad, int* __restrict__ jlist_g, int* __restrict__ M_g)
{
    const int b = blockIdx.x;
    const int tid = threadIdx.x;
    __shared__ int s_wcnt[8];
    __shared__ int s_wbase[8];
    const int wv = tid >> 6, lane = tid & 63;
    unsigned long long bm[2];
    #pragma unroll
    for (int cc = 0; cc < 2; ++cc) {
        const int j = cc * 256 + tid;
        const int ok = (pad[b * NSEQ + j] == 0);
        bm[cc] = __ballot(ok);
        if (lane == 0) s_wcnt[cc * 4 + wv] = __popcll(bm[cc]);
    }
    __syncthreads();
    if (tid == 0) {
        int acc = 0;
        #pragma unroll
        for (int q = 0; q < 8; ++q) { s_wbase[q] = acc; acc += s_wcnt[q]; }
        M_g[b] = acc;
    }
    __syncthreads();
    #pragma unroll
    for (int cc = 0; cc < 2; ++cc) {
        const int j = cc * 256 + tid;
        if (pad[b * NSEQ + j] == 0) {
            const int pos = s_wbase[cc * 4 + wv]
                          + __popcll(bm[cc] & ((1ull << lane) - 1ull));
            jlist_g[b * NSEQ + pos] = j;
        }
    }
}

// ---------------- Kernel 1: atom head + pj + pib, ROWG=4 rows/block (weight reuse; passes) ----------------
__global__ __launch_bounds__(256) void row_kernel(
    const float* __restrict__ trunk, const int* __restrict__ pad,
    const float* __restrict__ ln_g, const float* __restrict__ ln_b,
    const float* __restrict__ w_a1, const float* __restrict__ b_a1,
    const float* __restrict__ w_a2, const float* __restrict__ b_a2,
    const float* __restrict__ w_pi, const float* __restrict__ w_pj,
    const float* __restrict__ b_p1,
    float* __restrict__ out_atom, float* __restrict__ pj_o,
    unsigned short* __restrict__ pib_o)
{
    const int row0 = blockIdx.x * ROWG;
    const int tid = threadIdx.x;
    const int wv = tid >> 6, lane = tid & 63;
    __shared__ __align__(16) float x_t[D][ROWG];
    __shared__ __align__(16) float xn_t[D][ROWG];
    __shared__ float y[ROWG][D];
    __shared__ float mu_s[ROWG], rs_s[ROWG];

    #pragma unroll
    for (int g = 0; g < ROWG; ++g)
        x_t[tid][g] = trunk[(size_t)(row0 + g) * D + tid];
    __syncthreads();

    {
        const int g = wv;
        float s = 0.0f, ss = 0.0f;
        #pragma unroll
        for (int e = lane; e < D; e += 64) {
            const float v = x_t[e][g];
            s += v; ss += v * v;
        }
        #pragma unroll
        for (int off = 32; off; off >>= 1) {
            s  += __shfl_xor(s, off);
            ss += __shfl_xor(ss, off);
        }
        if (lane == 0) {
            const float mu  = s * (1.0f / D);
            const float var = ss * (1.0f / D) - mu * mu;
            mu_s[g] = mu;
            rs_s[g] = rsqrtf(var + 1e-5f);
        }
    }
    __syncthreads();
    {
        const float lg = ln_g[tid], lb = ln_b[tid];
        #pragma unroll
        for (int g = 0; g < ROWG; ++g)
            xn_t[tid][g] = (x_t[tid][g] - mu_s[g]) * rs_s[g] * lg + lb;
    }
    __syncthreads();

    {
        float acc0 = b_a1[tid], acc1 = acc0, acc2 = acc0, acc3 = acc0;
        for (int d = 0; d < D; ++d) {
            const float w = w_a1[d * D + tid];
            const float4 xv = *(const float4*)xn_t[d];
            acc0 = fmaf(xv.x, w, acc0);
            acc1 = fmaf(xv.y, w, acc1);
            acc2 = fmaf(xv.z, w, acc2);
            acc3 = fmaf(xv.w, w, acc3);
        }
        y[0][tid] = acc0 / (1.0f + expf(-acc0));
        y[1][tid] = acc1 / (1.0f + expf(-acc1));
        y[2][tid] = acc2 / (1.0f + expf(-acc2));
        y[3][tid] = acc3 / (1.0f + expf(-acc3));
    }

    float p0 = 0.0f, p1 = 0.0f, p2 = 0.0f, p3 = 0.0f;
    if (tid < H) {
        for (int d = 0; d < D; ++d) {
            const float w = w_pi[d * H + tid];
            const float4 xv = *(const float4*)x_t[d];
            p0 = fmaf(xv.x, w, p0);
            p1 = fmaf(xv.y, w, p1);
            p2 = fmaf(xv.z, w, p2);
            p3 = fmaf(xv.w, w, p3);
        }
        const float bb = b_p1[tid];
        p0 += bb; p1 += bb; p2 += bb; p3 += bb;
    } else {
        const int h = tid - H;
        for (int d = 0; d < D; ++d) {
            const float w = w_pj[d * H + h];
            const float4 xv = *(const float4*)x_t[d];
            p0 = fmaf(xv.x, w, p0);
            p1 = fmaf(xv.y, w, p1);
            p2 = fmaf(xv.z, w, p2);
            p3 = fmaf(xv.w, w, p3);
        }
    }
    __syncthreads();
    if (tid < H) {
        const float pv[ROWG] = {p0, p1, p2, p3};
        #pragma unroll
        for (int g = 0; g < ROWG; ++g) {
            const bf16 pb = __float2bfloat16(pv[g]);
            pib_o[(size_t)(row0 + g) * H + tid] = *(const unsigned short*)&pb;
        }
    } else {
        const int h = tid - H;
        const float pv[ROWG] = {p0, p1, p2, p3};
        #pragma unroll
        for (int g = 0; g < ROWG; ++g)
            pj_o[(size_t)(row0 + g) * H + h] = pv[g];
    }

    if (tid < ROWG * AC) {
        const int g = tid / AC, c = tid % AC;
        float a = b_a2[c];
        for (int d = 0; d < D; ++d) a = fmaf(y[g][d], w_a2[d * AC + c], a);
        out_atom[(row0 + g) * AC + c] = (pad[row0 + g] != 0) ? 0.0f : a;
    }
}

// per-pair inner body (inlined; all register state)
__device__ __forceinline__ void pair_body(
    const float pvx, const float pvy,
    const float* __restrict__ rbf_row, const float4 dk,
    const float pibx, const float piby,
    const float* wprA, const float* wprB, const float2 wp22,
    float& cdx, float& cdy, float& cdz,
    float& sdx, float& sdy, float& sdz)
{
    float t0a = pibx + pvx, t0b = 0.0f;
    float t1a = piby + pvy, t1b = 0.0f;
    #pragma unroll
    for (int r = 0; r < R; r += 2) {
        const float qa = rbf_row[r];
        const float qb = rbf_row[r + 1];
        t0a = fmaf(qa, wprA[r],     t0a);
        t0b = fmaf(qb, wprA[r + 1], t0b);
        t1a = fmaf(qa, wprB[r],     t1a);
        t1b = fmaf(qb, wprB[r + 1], t1b);
    }
    const float u0 = fast_silu(t0a + t0b);
    const float u1 = fast_silu(t1a + t1b);
    const float part = u0 * wp22.x + u1 * wp22.y;
    cdx = fmaf(part, dk.x, cdx);
    cdy = fmaf(part, dk.y, cdy);
    cdz = fmaf(part, dk.z, cdz);
    sdx += dk.x; sdy += dk.y; sdz += dk.z;
}

// ---------------- Kernel 2: pair head — SPLIT=4, 4-wide pv ILP ----------------
__global__ __launch_bounds__(256) void pair_kernel(
    const float* __restrict__ coords, const int* __restrict__ pad,
    const float* __restrict__ w_pr, const float* __restrict__ w_p2,
    const float* __restrict__ b_p2,
    const float* __restrict__ pj_i, const unsigned short* __restrict__ pib_i,
    const int* __restrict__ jlist_g, const int* __restrict__ M_g,
    float* __restrict__ cd_part)   // [BN][SPLIT][3]
{
    const int row  = blockIdx.x >> 2;
    const int part_id = blockIdx.x & 3;
    const int b = row >> 9;
    const int tid = threadIdx.x;

    if (pad[row] != 0) {
        if (tid == 0) {
            cd_part[(row * SPLIT + part_id) * 3 + 0] = 0.0f;
            cd_part[(row * SPLIT + part_id) * 3 + 1] = 0.0f;
            cd_part[(row * SPLIT + part_id) * 3 + 2] = 0.0f;
        }
        return;
    }

    __shared__ __align__(16) float s_rbf[CHUNK][20];
    __shared__ __align__(16) float4 s_d4[CHUNK];
    __shared__ int   s_jl[CHUNK];
    __shared__ float rw1[4], rw2[4], rw3[4];

    const int wv = tid >> 6, lane = tid & 63;
    const int M = M_g[b];
    const int Mq  = (M + SPLIT - 1) / SPLIT;
    const int kLo = part_id * Mq;
    const int kHi = min(M, kLo + Mq);

    float wprA[R], wprB[R];
    #pragma unroll
    for (int r = 0; r < R; ++r) {
        const float2 wv2 = ((const float2*)(w_pr + r * H))[lane];
        wprA[r] = wv2.x;
        wprB[r] = wv2.y;
    }
    const ushort2 pibu = ((const ushort2*)(pib_i + (size_t)row * H))[lane];
    const float pibx = bf2f(pibu.x), piby = bf2f(pibu.y);
    const float2 wp22 = ((const float2*)w_p2)[lane];
    const float bp2 = b_p2[0];
    const float cix = coords[(size_t)row * 3 + 0];
    const float ciy = coords[(size_t)row * 3 + 1];
    const float ciz = coords[(size_t)row * 3 + 2];

    float cdx = 0.0f, cdy = 0.0f, cdz = 0.0f;
    float sdx = 0.0f, sdy = 0.0f, sdz = 0.0f;
    const float* pjb = pj_i + (size_t)b * NSEQ * H;
    const float gamma = 14.0625f;  // (15/4)^2

    for (int c0 = kLo; c0 < kHi; c0 += CHUNK) {
        const int cn = (kHi - c0 < CHUNK) ? (kHi - c0) : CHUNK;
        __syncthreads();
        if (tid < cn) {
            const int j = jlist_g[b * NSEQ + c0 + tid];
            s_jl[tid] = j;
            const float* cj = coords + (size_t)(b * NSEQ + j) * 3;
            const float dx = cix - cj[0];
            const float dy = ciy - cj[1];
            const float dz = ciz - cj[2];
            const float sq = dx * dx + dy * dy + dz * dz;
            const float dist = sqrtf(fmaxf(sq, 1e-12f));
            s_d4[tid] = make_float4(dx, dy, dz, 0.0f);
            #pragma unroll
            for (int c = 0; c < 4; ++c) {
                float4 q;
                const float t0 = dist - (float)(4.0 * (4 * c + 0) / 15.0);
                const float t1 = dist - (float)(4.0 * (4 * c + 1) / 15.0);
                const float t2 = dist - (float)(4.0 * (4 * c + 2) / 15.0);
                const float t3 = dist - (float)(4.0 * (4 * c + 3) / 15.0);
                q.x = __expf(-gamma * t0 * t0);
                q.y = __expf(-gamma * t1 * t1);
                q.z = __expf(-gamma * t2 * t2);
                q.w = __expf(-gamma * t3 * t3);
                *(float4*)(&s_rbf[tid][4 * c]) = q;
            }
        }
        __syncthreads();
        // 4-wide ILP: 4 pv loads in flight per wave-iteration
        for (int k = wv; k < cn; k += 16) {
            const int k1 = k + 4, k2 = k + 8, k3 = k + 12;
            const bool h1 = (k1 < cn), h2 = (k2 < cn), h3 = (k3 < cn);
            const int j0 = s_jl[k];
            const int j1 = s_jl[h1 ? k1 : k];
            const int j2 = s_jl[h2 ? k2 : k];
            const int j3 = s_jl[h3 ? k3 : k];
            const float2 pv0 = ((const float2*)(pjb + (size_t)j0 * H))[lane];
            const float2 pv1 = ((const float2*)(pjb + (size_t)j1 * H))[lane];
            const float2 pv2 = ((const float2*)(pjb + (size_t)j2 * H))[lane];
            const float2 pv3 = ((const float2*)(pjb + (size_t)j3 * H))[lane];

            pair_body(pv0.x, pv0.y, s_rbf[k], s_d4[k], pibx, piby,
                      wprA, wprB, wp22, cdx, cdy, cdz, sdx, sdy, sdz);
            if (h1) pair_body(pv1.x, pv1.y, s_rbf[k1], s_d4[k1], pibx, piby,
                              wprA, wprB, wp22, cdx, cdy, cdz, sdx, sdy, sdz);
            if (h2) pair_body(pv2.x, pv2.y, s_rbf[k2], s_d4[k2], pibx, piby,
                              wprA, wprB, wp22, cdx, cdy, cdz, sdx, sdy, sdz);
            if (h3) pair_body(pv3.x, pv3.y, s_rbf[k3], s_d4[k3], pibx, piby,
                              wprA, wprB, wp22, cdx, cdy, cdz, sdx, sdy, sdz);
        }
    }
    #pragma unroll
    for (int off = 32; off; off >>= 1) {
        cdx += __shfl_xor(cdx, off);
        cdy += __shfl_xor(cdy, off);
        cdz += __shfl_xor(cdz, off);
    }
    if (lane == 0) {
        rw1[wv] = cdx + bp2 * sdx;
        rw2[wv] = cdy + bp2 * sdy;
        rw3[wv] = cdz + bp2 * sdz;
    }
    __syncthreads();
    if (tid == 0) {
        cd_part[(row * SPLIT + part_id) * 3 + 0] = rw1[0] + rw1[1] + rw1[2] + rw1[3];
        cd_part[(row * SPLIT + part_id) * 3 + 1] = rw2[0] + rw2[1] + rw2[2] + rw2[3];
        cd_part[(row * SPLIT + part_id) * 3 + 2] = rw3[0] + rw3[1] + rw3[2] + rw3[3];
    }
}

// ---------------- Kernel 3: proper jax finalize (sums SPLIT parts) ----------------
__global__ __launch_bounds__(256) void finalize_kernel(
    const float* __restrict__ cd_part, const int* __restrict__ pad,
    float* __restrict__ out_coord)
{
    const int b = blockIdx.x;
    const int tid = threadIdx.x;
    __shared__ float r1[256], r2[256], r3[256], r4[256];
    float sx = 0.0f, sy = 0.0f, sz = 0.0f, cnt = 0.0f;
    for (int ii = tid; ii < NSEQ; ii += 256) {
        const int row = b * NSEQ + ii;
        if (pad[row] == 0) {
            float cx = 0.0f, cy = 0.0f, cz = 0.0f;
            #pragma unroll
            for (int q = 0; q < SPLIT; ++q) {
                cx += cd_part[(row * SPLIT + q) * 3 + 0];
                cy += cd_part[(row * SPLIT + q) * 3 + 1];
                cz += cd_part[(row * SPLIT + q) * 3 + 2];
            }
            sx += cx; sy += cy; sz += cz;
            cnt += 1.0f;
        }
    }
    r1[tid] = sx; r2[tid] = sy; r3[tid] = sz; r4[tid] = cnt;
    __syncthreads();
    for (int s = 128; s > 0; s >>= 1) {
        if (tid < s) {
            r1[tid] += r1[tid + s]; r2[tid] += r2[tid + s];
            r3[tid] += r3[tid + s]; r4[tid] += r4[tid + s];
        }
        __syncthreads();
    }
    const float denom = fmaxf(r4[0], 1.0f);
    const float inv_d = 1.0f / denom;
    const float mx = r1[0] * inv_d * inv_d;
    const float my = r2[0] * inv_d * inv_d;
    const float mz = r3[0] * inv_d * inv_d;
    for (int ii = tid; ii < NSEQ; ii += 256) {
        const int row = b * NSEQ + ii;
        const bool v = (pad[row] == 0);
        float cx = 0.0f, cy = 0.0f, cz = 0.0f;
        #pragma unroll
        for (int q = 0; q < SPLIT; ++q) {
            cx += cd_part[(row * SPLIT + q) * 3 + 0];
            cy += cd_part[(row * SPLIT + q) * 3 + 1];
            cz += cd_part[(row * SPLIT + q) * 3 + 2];
        }
        out_coord[row * 3 + 0] = v ? cx * inv_d - mx : 0.0f;
        out_coord[row * 3 + 1] = v ? cy * inv_d - my : 0.0f;
        out_coord[row * 3 + 2] = v ? cz * inv_d - mz : 0.0f;
    }
}

extern "C" void kernel_launch(void* const* d_in, const int* in_sizes, int n_in,
                              void* d_out, int out_size, void* d_ws, size_t ws_size,
                              hipStream_t stream) {
    const float* trunk  = (const float*)d_in[0];
    const float* coords = (const float*)d_in[1];
    const int*   pad    = (const int*)d_in[2];
    const float* ln_g   = (const float*)d_in[3];
    const float* ln_b   = (const float*)d_in[4];
    const float* w_a1   = (const float*)d_in[5];
    const float* b_a1   = (const float*)d_in[6];
    const float* w_a2   = (const float*)d_in[7];
    const float* b_a2   = (const float*)d_in[8];
    const float* w_pi   = (const float*)d_in[9];
    const float* w_pj   = (const float*)d_in[10];
    const float* w_pr   = (const float*)d_in[11];
    const float* b_p1   = (const float*)d_in[12];
    const float* w_p2   = (const float*)d_in[13];
    const float* b_p2   = (const float*)d_in[14];

    float* out_atom  = (float*)d_out;                 // f32 [0:10240]
    float* out_coord = out_atom + (size_t)BN * AC;    // f32 [10240:16384]

    // ws layout: jlist[4*512] M[16] | cd_part[BN*SPLIT*3] | pj f32[BN*H] | pib bf16[BN*H]
    int*   jlist_g = (int*)d_ws;
    int*   M_g     = jlist_g + 4 * NSEQ;
    float* cd_part = (float*)(M_g + 16);
    float* pj_buf  = cd_part + (size_t)BN * SPLIT * 3;
    unsigned short* pib_buf = (unsigned short*)(pj_buf + (size_t)BN * H);

    batch_kernel<<<4, 256, 0, stream>>>(pad, jlist_g, M_g);
    row_kernel<<<BN / ROWG, 256, 0, stream>>>(trunk, pad, ln_g, ln_b, w_a1, b_a1,
                                              w_a2, b_a2, w_pi, w_pj, b_p1,
                                              out_atom, pj_buf, pib_buf);
    pair_kernel<<<BN * SPLIT, 256, 0, stream>>>(coords, pad, w_pr, w_p2, b_p2,
                                                pj_buf, pib_buf, jlist_g, M_g, cd_part);
    finalize_kernel<<<4, 256, 0, stream>>>(cd_part, pad, out_coord);
}